// Round 1
// baseline (231.873 us; speedup 1.0000x reference)
//
#include <hip/hip_runtime.h>
#include <hip/hip_bf16.h>

#define B_    8
#define S_    2048
#define D_    2048
#define DS_   64
#define NUSED 1536
#define TOK   16384  // B_*S_

// ws layout (float offsets)
static constexpr int WS_EMB  = 0;                    // e_t[64][1536]
static constexpr int WS_HT   = 64 * NUSED;           // h_t[64][16384]
static constexpr int WS_PART = WS_HT + 64 * TOK;     // part[512][1536]

// ---------------- K1: normalize embeddings, write transposed e_t[k][n] -----
__launch_bounds__(256)
__global__ void k_embnorm(const float* __restrict__ emb, float* __restrict__ et) {
    int n = blockIdx.x * 4 + (threadIdx.x >> 6);   // neuron 0..1535
    int k = threadIdx.x & 63;
    float v = emb[n * DS_ + k];
    float ss = v * v;
#pragma unroll
    for (int off = 32; off; off >>= 1) ss += __shfl_xor(ss, off);
    et[k * NUSED + n] = v / sqrtf(ss);
}

// ---------------- K2: h = x @ W^T + b, write h_t[k][token] ----------------
__launch_bounds__(256)
__global__ void k_gemm1(const float* __restrict__ x, const float* __restrict__ W,
                        const float* __restrict__ bias, float* __restrict__ ht) {
    __shared__ float xt[32][68];  // xt[k][m] padded
    __shared__ float wt[32][68];  // wt[k][n]
    const int tid = threadIdx.x;
    const int m0  = blockIdx.x * 64;
    const int tx  = tid & 15, ty = tid >> 4;
    const int r0  = tid >> 3, c0 = tid & 7;   // loader: rows r0 and r0+32, float4 col c0

    const float4* x4 = reinterpret_cast<const float4*>(x);
    const float4* w4 = reinterpret_cast<const float4*>(W);

    float acc[4][4] = {};
    float4 rx0, rx1, rw0, rw1;
    rx0 = x4[(m0 + r0) * 512 + c0];
    rx1 = x4[(m0 + r0 + 32) * 512 + c0];
    rw0 = w4[r0 * 512 + c0];
    rw1 = w4[(r0 + 32) * 512 + c0];

    for (int kt = 0; kt < 64; ++kt) {
        {   // regs -> LDS (transposed)
            const float* p0 = reinterpret_cast<const float*>(&rx0);
            const float* p1 = reinterpret_cast<const float*>(&rx1);
            const float* q0 = reinterpret_cast<const float*>(&rw0);
            const float* q1 = reinterpret_cast<const float*>(&rw1);
#pragma unroll
            for (int j = 0; j < 4; ++j) {
                xt[c0 * 4 + j][r0]      = p0[j];
                xt[c0 * 4 + j][r0 + 32] = p1[j];
                wt[c0 * 4 + j][r0]      = q0[j];
                wt[c0 * 4 + j][r0 + 32] = q1[j];
            }
        }
        __syncthreads();
        if (kt < 63) {  // prefetch next K-tile
            int k4 = (kt + 1) * 8;
            rx0 = x4[(m0 + r0) * 512 + k4 + c0];
            rx1 = x4[(m0 + r0 + 32) * 512 + k4 + c0];
            rw0 = w4[r0 * 512 + k4 + c0];
            rw1 = w4[(r0 + 32) * 512 + k4 + c0];
        }
#pragma unroll
        for (int kk = 0; kk < 32; ++kk) {
            float4 a  = *reinterpret_cast<const float4*>(&xt[kk][ty * 4]);
            float4 bb = *reinterpret_cast<const float4*>(&wt[kk][tx * 4]);
            float av[4] = {a.x, a.y, a.z, a.w};
            float bv[4] = {bb.x, bb.y, bb.z, bb.w};
#pragma unroll
            for (int i = 0; i < 4; ++i)
#pragma unroll
                for (int j = 0; j < 4; ++j)
                    acc[i][j] = fmaf(av[i], bv[j], acc[i][j]);
        }
        __syncthreads();
    }
#pragma unroll
    for (int j = 0; j < 4; ++j) {
        float bj = bias[tx * 4 + j];
#pragma unroll
        for (int i = 0; i < 4; ++i)
            ht[(tx * 4 + j) * TOK + m0 + ty * 4 + i] = acc[i][j] + bj;
    }
}

// ---------------- K3: logits -> slice softmax -> importance-weighted dense -
__launch_bounds__(256)
__global__ void k_route(const float* __restrict__ ht, const float* __restrict__ et,
                        const float* __restrict__ imp, float* __restrict__ part) {
    __shared__ float h_l[64][32];     // h_l[k][t]
    __shared__ float e_l[64][128];    // e_l[k][n]
    __shared__ float lg[32][516];     // logits (then p=exp) per token, padded stride
    __shared__ float dens[1536];
    __shared__ float mbuf[32], zbuf[32], coef[32], impb[32];

    const int tid = threadIdx.x;
    const int b = blockIdx.x >> 6, ch = blockIdx.x & 63;
    const int tb = b * S_ + ch * 32;

    {   // load h tile [64 k][32 t]
        const float4* h4 = reinterpret_cast<const float4*>(ht);
#pragma unroll
        for (int r = 0; r < 2; ++r) {
            int idx = tid + 256 * r;
            int k = idx >> 3, t4 = idx & 7;
            *reinterpret_cast<float4*>(&h_l[k][t4 * 4]) = h4[k * 4096 + (tb >> 2) + t4];
        }
    }
    if (tid < 32) impb[tid] = imp[tb + tid];
#pragma unroll
    for (int i = 0; i < 6; ++i) dens[tid + 256 * i] = 0.f;
    __syncthreads();

    const int soffs[4] = {0, 512, 1024, 1280};
    const int ssz[4]   = {512, 512, 256, 256};
    const int tn = tid & 31, tt = tid >> 5;

    for (int sl = 0; sl < 4; ++sl) {
        const int soff = soffs[sl], Sn = ssz[sl];
        for (int nt = 0; nt < Sn / 128; ++nt) {
            const int ngl = soff + nt * 128;
            __syncthreads();  // prior users of e_l / lg done
            {   // load e tile [64 k][128 n]
                const float4* e4 = reinterpret_cast<const float4*>(et);
#pragma unroll
                for (int r = 0; r < 8; ++r) {
                    int idx = tid + 256 * r;
                    int k = idx >> 5, j4 = idx & 31;
                    *reinterpret_cast<float4*>(&e_l[k][j4 * 4]) = e4[k * 384 + (ngl >> 2) + j4];
                }
            }
            __syncthreads();
            float acc[4][4] = {};
            for (int k = 0; k < 64; ++k) {
                float4 a  = *reinterpret_cast<const float4*>(&h_l[k][tt * 4]);
                float4 bb = *reinterpret_cast<const float4*>(&e_l[k][tn * 4]);
                float av[4] = {a.x, a.y, a.z, a.w};
                float bv[4] = {bb.x, bb.y, bb.z, bb.w};
#pragma unroll
                for (int i = 0; i < 4; ++i)
#pragma unroll
                    for (int j = 0; j < 4; ++j)
                        acc[i][j] = fmaf(av[i], bv[j], acc[i][j]);
            }
#pragma unroll
            for (int i = 0; i < 4; ++i)
                *reinterpret_cast<float4*>(&lg[tt * 4 + i][nt * 128 + tn * 4]) =
                    make_float4(acc[i][0], acc[i][1], acc[i][2], acc[i][3]);
        }
        __syncthreads();  // lg complete for whole slice

        const int t = tid >> 3, j = tid & 7;
        float m = -1e30f;
        for (int i = j; i < Sn; i += 8) m = fmaxf(m, lg[t][i]);
#pragma unroll
        for (int off = 1; off < 8; off <<= 1) m = fmaxf(m, __shfl_xor(m, off));
        if (j == 0) mbuf[t] = m;
        __syncthreads();

        const float mt = mbuf[t];
        float z = 0.f;
        for (int i = j; i < Sn; i += 8) {
            float p = __expf(lg[t][i] - mt);
            lg[t][i] = p;
            z += p;
        }
#pragma unroll
        for (int off = 1; off < 8; off <<= 1) z += __shfl_xor(z, off);
        if (j == 0) zbuf[t] = z;
        __syncthreads();
        if (tid < 32) coef[tid] = impb[tid] / zbuf[tid];
        __syncthreads();

        for (int n = tid; n < Sn; n += 256) {
            float s = 0.f;
#pragma unroll 8
            for (int t2 = 0; t2 < 32; ++t2) s = fmaf(coef[t2], lg[t2][n], s);
            dens[soff + n] += s;
        }
        // next slice's first e-load barrier protects lg reuse
    }
    __syncthreads();
#pragma unroll
    for (int i = 0; i < 6; ++i) {
        int n = tid + 256 * i;
        part[blockIdx.x * 1536 + n] = dens[n];
    }
}

// ---------------- K4: reduce partials, top-k sparsify, write output -------
__launch_bounds__(256)
__global__ void k_final(const float* __restrict__ part, float* __restrict__ out) {
    __shared__ float dens[1536];
    __shared__ float s_v[4][8];
    __shared__ int   s_n[4][8];
    const int tid = threadIdx.x;
    const int b = blockIdx.x;

#pragma unroll
    for (int i = 0; i < 6; ++i) {
        int n = tid + 256 * i;
        float s = 0.f;
        for (int c = 0; c < 64; ++c) s += part[(b * 64 + c) * 1536 + n];
        dens[n] = s;
    }
    for (int i = tid; i < 1792; i += 256) out[b * 1792 + i] = 0.f;
    __syncthreads();

    const int w = tid >> 6, lane = tid & 63;
    const int soffs[4] = {0, 512, 1024, 1280};
    const int ssz[4]   = {512, 512, 256, 256};
    const int kks[4]   = {8, 8, 4, 6};
    const int ooffs[4] = {0, 512, 1024, 1536};
    const int Sn = ssz[w], soff = soffs[w], kk = kks[w];
    const int nslots = Sn >> 6;

    float v[8];
#pragma unroll
    for (int i = 0; i < 8; ++i)
        v[i] = (i < nslots) ? dens[soff + lane + 64 * i] : -1e30f;

    unsigned rm = 0;
    float ssum = 0.f;
    for (int it = 0; it < kk; ++it) {
        float bv = -1e30f;
        int bn = 0x7fffffff;
#pragma unroll
        for (int i = 0; i < 8; ++i) {
            bool valid = (i < nslots) && !((rm >> i) & 1u);
            if (valid && v[i] > bv) { bv = v[i]; bn = lane + 64 * i; }
        }
#pragma unroll
        for (int off = 32; off; off >>= 1) {
            float ov = __shfl_xor(bv, off);
            int   on = __shfl_xor(bn, off);
            if (ov > bv || (ov == bv && on < bn)) { bv = ov; bn = on; }
        }
        ssum += bv;
        if ((bn & 63) == lane) rm |= 1u << (bn >> 6);
        if (lane == 0) { s_v[w][it] = bv; s_n[w][it] = bn; }
    }
    const float inv = 1.f / (ssum + 1e-8f);
    if (lane < kk) {
        int n = s_n[w][lane];
        float val = s_v[w][lane] * inv;
        out[b * 1792 + ooffs[w] + n] = val;
        if (w == 2) out[b * 1792 + 1280 + n] = val;  // rk = rq
    }
}

extern "C" void kernel_launch(void* const* d_in, const int* in_sizes, int n_in,
                              void* d_out, int out_size, void* d_ws, size_t ws_size,
                              hipStream_t stream) {
    const float* x    = (const float*)d_in[0];
    const float* imp  = (const float*)d_in[1];
    const float* W    = (const float*)d_in[2];
    const float* bias = (const float*)d_in[3];
    const float* emb  = (const float*)d_in[4];
    float* out = (float*)d_out;
    float* ws  = (float*)d_ws;

    float* et   = ws + WS_EMB;
    float* ht   = ws + WS_HT;
    float* part = ws + WS_PART;

    k_embnorm<<<NUSED / 4, 256, 0, stream>>>(emb, et);
    k_gemm1<<<TOK / 64, 256, 0, stream>>>(x, W, bias, ht);
    k_route<<<512, 256, 0, stream>>>(ht, et, imp, part);
    k_final<<<B_, 256, 0, stream>>>(part, out);
}

// Round 2
// 156.716 us; speedup vs baseline: 1.4796x; 1.4796x over previous
//
#include <hip/hip_runtime.h>
#include <hip/hip_bf16.h>

#define B_    8
#define S_    2048
#define D_    2048
#define DS_   64
#define NUSED 1536
#define TOK   16384  // B_*S_

// ws layout (float offsets)
static constexpr int WS_EMB   = 0;                         // e_t[64][1536]
static constexpr int WS_HT    = 64 * NUSED;                // htp[4][64][16384]
static constexpr int WS_PART  = WS_HT + 4 * 64 * TOK;      // part[1024][1536]
static constexpr int WS_PART2 = WS_PART + 1024 * NUSED;    // part2[64][1536]

// ---------------- K1: normalize embeddings, write transposed e_t[k][n] -----
__launch_bounds__(256)
__global__ void k_embnorm(const float* __restrict__ emb, float* __restrict__ et) {
    int n = blockIdx.x * 4 + (threadIdx.x >> 6);   // neuron 0..1535
    int k = threadIdx.x & 63;
    float v = emb[n * DS_ + k];
    float ss = v * v;
#pragma unroll
    for (int off = 32; off; off >>= 1) ss += __shfl_xor(ss, off);
    et[k * NUSED + n] = v / sqrtf(ss);
}

// ---------------- K2: partial h = x @ W^T (K-split 4), no bias -------------
__launch_bounds__(256, 4)
__global__ void k_gemm1(const float* __restrict__ x, const float* __restrict__ W,
                        float* __restrict__ htp) {
    __shared__ float xt[32][68];  // xt[k][m] padded
    __shared__ float wt[32][68];  // wt[k][n]
    const int tid   = threadIdx.x;
    const int split = blockIdx.x & 3;
    const int m0    = (blockIdx.x >> 2) * 64;
    const int k0    = split * 128;             // in float4 units (512 floats)
    const int tx    = tid & 15, ty = tid >> 4;
    const int r0    = tid >> 3, c0 = tid & 7;

    const float4* x4 = reinterpret_cast<const float4*>(x);
    const float4* w4 = reinterpret_cast<const float4*>(W);

    float acc[4][4] = {};
    float4 rx0 = x4[(m0 + r0) * 512 + k0 + c0];
    float4 rx1 = x4[(m0 + r0 + 32) * 512 + k0 + c0];
    float4 rw0 = w4[r0 * 512 + k0 + c0];
    float4 rw1 = w4[(r0 + 32) * 512 + k0 + c0];

    for (int kt = 0; kt < 16; ++kt) {
        {   // regs -> LDS (transposed)
            const float* p0 = reinterpret_cast<const float*>(&rx0);
            const float* p1 = reinterpret_cast<const float*>(&rx1);
            const float* q0 = reinterpret_cast<const float*>(&rw0);
            const float* q1 = reinterpret_cast<const float*>(&rw1);
#pragma unroll
            for (int j = 0; j < 4; ++j) {
                xt[c0 * 4 + j][r0]      = p0[j];
                xt[c0 * 4 + j][r0 + 32] = p1[j];
                wt[c0 * 4 + j][r0]      = q0[j];
                wt[c0 * 4 + j][r0 + 32] = q1[j];
            }
        }
        __syncthreads();
        if (kt < 15) {  // prefetch next K-tile
            int k4 = k0 + (kt + 1) * 8;
            rx0 = x4[(m0 + r0) * 512 + k4 + c0];
            rx1 = x4[(m0 + r0 + 32) * 512 + k4 + c0];
            rw0 = w4[r0 * 512 + k4 + c0];
            rw1 = w4[(r0 + 32) * 512 + k4 + c0];
        }
#pragma unroll
        for (int kk = 0; kk < 32; ++kk) {
            float4 a  = *reinterpret_cast<const float4*>(&xt[kk][ty * 4]);
            float4 bb = *reinterpret_cast<const float4*>(&wt[kk][tx * 4]);
            float av[4] = {a.x, a.y, a.z, a.w};
            float bv[4] = {bb.x, bb.y, bb.z, bb.w};
#pragma unroll
            for (int i = 0; i < 4; ++i)
#pragma unroll
                for (int j = 0; j < 4; ++j)
                    acc[i][j] = fmaf(av[i], bv[j], acc[i][j]);
        }
        __syncthreads();
    }
#pragma unroll
    for (int j = 0; j < 4; ++j)
#pragma unroll
        for (int i = 0; i < 4; ++i)
            htp[(split * 64 + tx * 4 + j) * TOK + m0 + ty * 4 + i] = acc[i][j];
}

// ---------------- K3: logits -> exp -> z -> weighted dense, all in regs ----
// 16 tokens per block; thread owns 16 tokens x {2 or 1} neurons.
__launch_bounds__(256, 4)
__global__ void k_route(const float* __restrict__ htp, const float* __restrict__ bias,
                        const float* __restrict__ et, const float* __restrict__ imp,
                        float* __restrict__ part) {
    __shared__ float h_l[64][16];
    __shared__ float zw[4][16];
    __shared__ float coef[16];
    __shared__ float impb[16];

    const int tid = threadIdx.x;
    const int blk = blockIdx.x;
    const int tb  = blk * 16;
    const int w   = tid >> 6;

    {   // h = sum of 4 K-split partials + bias -> LDS
        const int k  = tid >> 2;
        const int t4 = (tid & 3) << 2;
        const float4* hp = reinterpret_cast<const float4*>(htp);
        const int col = (tb + t4) >> 2;
        float4 a = hp[(k      ) * 4096 + col];
        float4 b = hp[(k +  64) * 4096 + col];
        float4 c = hp[(k + 128) * 4096 + col];
        float4 d = hp[(k + 192) * 4096 + col];
        float bk = bias[k];
        float4 s;
        s.x = a.x + b.x + c.x + d.x + bk;
        s.y = a.y + b.y + c.y + d.y + bk;
        s.z = a.z + b.z + c.z + d.z + bk;
        s.w = a.w + b.w + c.w + d.w + bk;
        *reinterpret_cast<float4*>(&h_l[k][t4]) = s;
    }
    if (tid < 16) impb[tid] = imp[tb + tid];
    __syncthreads();

    float acc0[16], acc1[16];
    const int soffs[4] = {0, 512, 1024, 1280};

#pragma unroll 1
    for (int sl = 0; sl < 4; ++sl) {
        const int soff = soffs[sl];
        const bool wide = (sl < 2);   // 512-neuron slices: 2 neurons/thread

#pragma unroll
        for (int t = 0; t < 16; ++t) { acc0[t] = 0.f; acc1[t] = 0.f; }

        if (wide) {
            const float* ep = et + soff + tid * 2;
#pragma unroll 4
            for (int k = 0; k < 64; ++k) {
                const float2 ev = *reinterpret_cast<const float2*>(ep + k * NUSED);
                const float4 h0 = *reinterpret_cast<const float4*>(&h_l[k][0]);
                const float4 h1 = *reinterpret_cast<const float4*>(&h_l[k][4]);
                const float4 h2 = *reinterpret_cast<const float4*>(&h_l[k][8]);
                const float4 h3 = *reinterpret_cast<const float4*>(&h_l[k][12]);
                acc0[0]  = fmaf(h0.x, ev.x, acc0[0]);   acc1[0]  = fmaf(h0.x, ev.y, acc1[0]);
                acc0[1]  = fmaf(h0.y, ev.x, acc0[1]);   acc1[1]  = fmaf(h0.y, ev.y, acc1[1]);
                acc0[2]  = fmaf(h0.z, ev.x, acc0[2]);   acc1[2]  = fmaf(h0.z, ev.y, acc1[2]);
                acc0[3]  = fmaf(h0.w, ev.x, acc0[3]);   acc1[3]  = fmaf(h0.w, ev.y, acc1[3]);
                acc0[4]  = fmaf(h1.x, ev.x, acc0[4]);   acc1[4]  = fmaf(h1.x, ev.y, acc1[4]);
                acc0[5]  = fmaf(h1.y, ev.x, acc0[5]);   acc1[5]  = fmaf(h1.y, ev.y, acc1[5]);
                acc0[6]  = fmaf(h1.z, ev.x, acc0[6]);   acc1[6]  = fmaf(h1.z, ev.y, acc1[6]);
                acc0[7]  = fmaf(h1.w, ev.x, acc0[7]);   acc1[7]  = fmaf(h1.w, ev.y, acc1[7]);
                acc0[8]  = fmaf(h2.x, ev.x, acc0[8]);   acc1[8]  = fmaf(h2.x, ev.y, acc1[8]);
                acc0[9]  = fmaf(h2.y, ev.x, acc0[9]);   acc1[9]  = fmaf(h2.y, ev.y, acc1[9]);
                acc0[10] = fmaf(h2.z, ev.x, acc0[10]);  acc1[10] = fmaf(h2.z, ev.y, acc1[10]);
                acc0[11] = fmaf(h2.w, ev.x, acc0[11]);  acc1[11] = fmaf(h2.w, ev.y, acc1[11]);
                acc0[12] = fmaf(h3.x, ev.x, acc0[12]);  acc1[12] = fmaf(h3.x, ev.y, acc1[12]);
                acc0[13] = fmaf(h3.y, ev.x, acc0[13]);  acc1[13] = fmaf(h3.y, ev.y, acc1[13]);
                acc0[14] = fmaf(h3.z, ev.x, acc0[14]);  acc1[14] = fmaf(h3.z, ev.y, acc1[14]);
                acc0[15] = fmaf(h3.w, ev.x, acc0[15]);  acc1[15] = fmaf(h3.w, ev.y, acc1[15]);
            }
        } else {
            const float* ep = et + soff + tid;
#pragma unroll 4
            for (int k = 0; k < 64; ++k) {
                const float ev = ep[k * NUSED];
                const float4 h0 = *reinterpret_cast<const float4*>(&h_l[k][0]);
                const float4 h1 = *reinterpret_cast<const float4*>(&h_l[k][4]);
                const float4 h2 = *reinterpret_cast<const float4*>(&h_l[k][8]);
                const float4 h3 = *reinterpret_cast<const float4*>(&h_l[k][12]);
                acc0[0]  = fmaf(h0.x, ev, acc0[0]);
                acc0[1]  = fmaf(h0.y, ev, acc0[1]);
                acc0[2]  = fmaf(h0.z, ev, acc0[2]);
                acc0[3]  = fmaf(h0.w, ev, acc0[3]);
                acc0[4]  = fmaf(h1.x, ev, acc0[4]);
                acc0[5]  = fmaf(h1.y, ev, acc0[5]);
                acc0[6]  = fmaf(h1.z, ev, acc0[6]);
                acc0[7]  = fmaf(h1.w, ev, acc0[7]);
                acc0[8]  = fmaf(h2.x, ev, acc0[8]);
                acc0[9]  = fmaf(h2.y, ev, acc0[9]);
                acc0[10] = fmaf(h2.z, ev, acc0[10]);
                acc0[11] = fmaf(h2.w, ev, acc0[11]);
                acc0[12] = fmaf(h3.x, ev, acc0[12]);
                acc0[13] = fmaf(h3.y, ev, acc0[13]);
                acc0[14] = fmaf(h3.z, ev, acc0[14]);
                acc0[15] = fmaf(h3.w, ev, acc0[15]);
            }
        }

        // exp (no max-subtraction: |logit| <= ||h|| ~ 11, safe in fp32)
        float zp[16];
        if (wide) {
#pragma unroll
            for (int t = 0; t < 16; ++t) {
                acc0[t] = __expf(acc0[t]);
                acc1[t] = __expf(acc1[t]);
                zp[t] = acc0[t] + acc1[t];
            }
        } else {
#pragma unroll
            for (int t = 0; t < 16; ++t) {
                acc0[t] = __expf(acc0[t]);
                zp[t] = acc0[t];
            }
        }

        // 64-lane butterfly reduce of the 16 per-token z partials
#pragma unroll
        for (int off = 1; off < 64; off <<= 1) {
#pragma unroll
            for (int t = 0; t < 16; ++t) zp[t] += __shfl_xor(zp[t], off);
        }
        __syncthreads();   // prior slice's zw/coef consumers done
        if ((tid & 63) == 0) {
            *reinterpret_cast<float4*>(&zw[w][0])  = make_float4(zp[0],  zp[1],  zp[2],  zp[3]);
            *reinterpret_cast<float4*>(&zw[w][4])  = make_float4(zp[4],  zp[5],  zp[6],  zp[7]);
            *reinterpret_cast<float4*>(&zw[w][8])  = make_float4(zp[8],  zp[9],  zp[10], zp[11]);
            *reinterpret_cast<float4*>(&zw[w][12]) = make_float4(zp[12], zp[13], zp[14], zp[15]);
        }
        __syncthreads();
        if (tid < 16) {
            float z = zw[0][tid] + zw[1][tid] + zw[2][tid] + zw[3][tid];
            coef[tid] = impb[tid] / z;
        }
        __syncthreads();

        float cf[16];
#pragma unroll
        for (int t = 0; t < 16; t += 4) {
            float4 c4 = *reinterpret_cast<const float4*>(&coef[t]);
            cf[t] = c4.x; cf[t + 1] = c4.y; cf[t + 2] = c4.z; cf[t + 3] = c4.w;
        }
        float d0 = 0.f, d1 = 0.f;
#pragma unroll
        for (int t = 0; t < 16; ++t) {
            d0 = fmaf(cf[t], acc0[t], d0);
            d1 = fmaf(cf[t], acc1[t], d1);
        }
        if (wide) {
            *reinterpret_cast<float2*>(&part[blk * NUSED + soff + tid * 2]) = make_float2(d0, d1);
        } else {
            part[blk * NUSED + soff + tid] = d0;
        }
    }
}

// ---------------- K4a: reduce part 1024 -> 64 rows -------------------------
__launch_bounds__(256)
__global__ void kA(const float* __restrict__ part, float* __restrict__ part2) {
    const int tid = threadIdx.x;
    const int b = blockIdx.x >> 3, g = blockIdx.x & 7;
    const int base = (b * 128 + g * 16) * NUSED;
#pragma unroll
    for (int i = 0; i < 6; ++i) {
        int n = tid + 256 * i;
        float s = 0.f;
#pragma unroll
        for (int r = 0; r < 16; ++r) s += part[base + r * NUSED + n];
        part2[(b * 8 + g) * NUSED + n] = s;
    }
}

// ---------------- K4b: final reduce + top-k sparsify + output --------------
__launch_bounds__(256)
__global__ void kB(const float* __restrict__ part2, float* __restrict__ out) {
    __shared__ float dens[NUSED];
    __shared__ float s_v[4][8];
    __shared__ int   s_n[4][8];
    const int tid = threadIdx.x;
    const int b = blockIdx.x;

#pragma unroll
    for (int i = 0; i < 6; ++i) {
        int n = tid + 256 * i;
        float s = 0.f;
#pragma unroll
        for (int g = 0; g < 8; ++g) s += part2[(b * 8 + g) * NUSED + n];
        dens[n] = s;
    }
    for (int i = tid; i < 1792; i += 256) out[b * 1792 + i] = 0.f;
    __syncthreads();

    const int w = tid >> 6, lane = tid & 63;
    const int soffs[4] = {0, 512, 1024, 1280};
    const int ssz[4]   = {512, 512, 256, 256};
    const int kks[4]   = {8, 8, 4, 6};
    const int ooffs[4] = {0, 512, 1024, 1536};
    const int Sn = ssz[w], soff = soffs[w], kk = kks[w];
    const int nslots = Sn >> 6;

    float v[8];
#pragma unroll
    for (int i = 0; i < 8; ++i)
        v[i] = (i < nslots) ? dens[soff + lane + 64 * i] : -1e30f;

    unsigned rm = 0;
    float ssum = 0.f;
    for (int it = 0; it < kk; ++it) {
        float bv = -1e30f;
        int bn = 0x7fffffff;
#pragma unroll
        for (int i = 0; i < 8; ++i) {
            bool valid = (i < nslots) && !((rm >> i) & 1u);
            if (valid && v[i] > bv) { bv = v[i]; bn = lane + 64 * i; }
        }
#pragma unroll
        for (int off = 32; off; off >>= 1) {
            float ov = __shfl_xor(bv, off);
            int   on = __shfl_xor(bn, off);
            if (ov > bv || (ov == bv && on < bn)) { bv = ov; bn = on; }
        }
        ssum += bv;
        if ((bn & 63) == lane) rm |= 1u << (bn >> 6);
        if (lane == 0) { s_v[w][it] = bv; s_n[w][it] = bn; }
    }
    const float inv = 1.f / (ssum + 1e-8f);
    if (lane < kk) {
        int n = s_n[w][lane];
        float val = s_v[w][lane] * inv;
        out[b * 1792 + ooffs[w] + n] = val;
        if (w == 2) out[b * 1792 + 1280 + n] = val;  // rk = rq
    }
}

extern "C" void kernel_launch(void* const* d_in, const int* in_sizes, int n_in,
                              void* d_out, int out_size, void* d_ws, size_t ws_size,
                              hipStream_t stream) {
    const float* x    = (const float*)d_in[0];
    const float* imp  = (const float*)d_in[1];
    const float* W    = (const float*)d_in[2];
    const float* bias = (const float*)d_in[3];
    const float* emb  = (const float*)d_in[4];
    float* out = (float*)d_out;
    float* ws  = (float*)d_ws;

    float* et    = ws + WS_EMB;
    float* htp   = ws + WS_HT;
    float* part  = ws + WS_PART;
    float* part2 = ws + WS_PART2;

    k_embnorm<<<NUSED / 4, 256, 0, stream>>>(emb, et);
    k_gemm1<<<1024, 256, 0, stream>>>(x, W, htp);
    k_route<<<1024, 256, 0, stream>>>(htp, bias, et, imp, part);
    kA<<<64, 256, 0, stream>>>(part, part2);
    kB<<<8, 256, 0, stream>>>(part2, out);
}

// Round 3
// 124.357 us; speedup vs baseline: 1.8646x; 1.2602x over previous
//
#include <hip/hip_runtime.h>
#include <hip/hip_bf16.h>

#define B_    8
#define S_    2048
#define D_    2048
#define DS_   64
#define NUSED 1536
#define TOK   16384  // B_*S_

typedef __attribute__((ext_vector_type(8))) short bf16x8;
typedef __attribute__((ext_vector_type(4))) float f32x4;

// ws layout (float offsets)
static constexpr int WS_EMB   = 0;                           // e_t[64][1536]
static constexpr int WS_HT    = 64 * NUSED;                  // htp[2][64][16384]
static constexpr int WS_PART  = WS_HT + 2 * 64 * TOK;        // part[1024][1536]
static constexpr int WS_PART2 = WS_PART + 1024 * NUSED;      // part2[64][1536]
static constexpr int WS_WF    = WS_PART2 + 64 * NUSED;       // wfrag: 262144 shorts

__device__ inline short bf_hi(float f, float& rhi) {
    __hip_bfloat16 h = __float2bfloat16(f);
    rhi = __bfloat162float(h);
    return __builtin_bit_cast(short, h);
}
__device__ inline short bf_of(float f) {
    __hip_bfloat16 h = __float2bfloat16(f);
    return __builtin_bit_cast(short, h);
}

// ---------------- K0: W -> fragment-ready bf16 hi/lo ----------------------
// wfrag[kstep 64][msub 4][lane 64][8 hi | 8 lo] (shorts)
__launch_bounds__(256)
__global__ void k_wsplit(const float* __restrict__ W, short* __restrict__ wfrag) {
    const int t = threadIdx.x, kstep = blockIdx.x;
    const int msub = t >> 6, lane = t & 63;
    const int m = msub * 16 + (lane & 15);
    const float* wp = W + m * D_ + kstep * 32 + (lane >> 4) * 8;
    float4 a = *reinterpret_cast<const float4*>(wp);
    float4 b = *reinterpret_cast<const float4*>(wp + 4);
    float f[8] = {a.x, a.y, a.z, a.w, b.x, b.y, b.z, b.w};
    bf16x8 hi, lo;
#pragma unroll
    for (int j = 0; j < 8; ++j) {
        float r;
        hi[j] = bf_hi(f[j], r);
        lo[j] = bf_of(f[j] - r);
    }
    short* dst = wfrag + (((kstep << 2) | msub) * 64 + lane) * 16;
    *reinterpret_cast<bf16x8*>(dst)     = hi;
    *reinterpret_cast<bf16x8*>(dst + 8) = lo;
}

// ---------------- K1: normalize embeddings, write transposed e_t[k][n] -----
__launch_bounds__(256)
__global__ void k_embnorm(const float* __restrict__ emb, float* __restrict__ et) {
    int n = blockIdx.x * 4 + (threadIdx.x >> 6);   // neuron 0..1535
    int k = threadIdx.x & 63;
    float v = emb[n * DS_ + k];
    float ss = v * v;
#pragma unroll
    for (int off = 32; off; off >>= 1) ss += __shfl_xor(ss, off);
    et[k * NUSED + n] = v / sqrtf(ss);
}

// ---------------- K2: h^T = W @ x^T via split-bf16 MFMA (K-split 2) --------
#define MFMA16(A, Bv, C) __builtin_amdgcn_mfma_f32_16x16x32_bf16(A, Bv, C, 0, 0, 0)

__launch_bounds__(256, 2)
__global__ void k_gemm1(const float* __restrict__ x, const short* __restrict__ wfrag,
                        float* __restrict__ htp) {
    const int tid   = threadIdx.x;
    const int split = blockIdx.x & 1;
    const int tb    = (blockIdx.x >> 1) * 64;
    const int wave  = tid >> 6, lane = tid & 63;
    const int tok   = tb + wave * 16 + (lane & 15);

    const float* xp = x + (size_t)tok * D_ + split * 1024 + (lane >> 4) * 8;
    const short* wp = wfrag + split * 32 * 4096 + lane * 16;

    f32x4 acc0 = {0.f, 0.f, 0.f, 0.f};
    f32x4 acc1 = acc0, acc2 = acc0, acc3 = acc0;

    float4 xa = *reinterpret_cast<const float4*>(xp);
    float4 xb = *reinterpret_cast<const float4*>(xp + 4);

#pragma unroll 2
    for (int ks = 0; ks < 32; ++ks) {
        const short* wk = wp + ks * 4096;
        bf16x8 ah0 = *reinterpret_cast<const bf16x8*>(wk);
        bf16x8 al0 = *reinterpret_cast<const bf16x8*>(wk + 8);
        bf16x8 ah1 = *reinterpret_cast<const bf16x8*>(wk + 1024);
        bf16x8 al1 = *reinterpret_cast<const bf16x8*>(wk + 1032);
        bf16x8 ah2 = *reinterpret_cast<const bf16x8*>(wk + 2048);
        bf16x8 al2 = *reinterpret_cast<const bf16x8*>(wk + 2056);
        bf16x8 ah3 = *reinterpret_cast<const bf16x8*>(wk + 3072);
        bf16x8 al3 = *reinterpret_cast<const bf16x8*>(wk + 3080);

        float xf[8] = {xa.x, xa.y, xa.z, xa.w, xb.x, xb.y, xb.z, xb.w};
        bf16x8 bh, bl;
#pragma unroll
        for (int j = 0; j < 8; ++j) {
            float r;
            bh[j] = bf_hi(xf[j], r);
            bl[j] = bf_of(xf[j] - r);
        }
        if (ks < 31) {  // prefetch next x slab while MFMAs run
            xa = *reinterpret_cast<const float4*>(xp + (ks + 1) * 32);
            xb = *reinterpret_cast<const float4*>(xp + (ks + 1) * 32 + 4);
        }
        acc0 = MFMA16(ah0, bh, acc0);
        acc1 = MFMA16(ah1, bh, acc1);
        acc2 = MFMA16(ah2, bh, acc2);
        acc3 = MFMA16(ah3, bh, acc3);
        acc0 = MFMA16(al0, bh, acc0);
        acc1 = MFMA16(al1, bh, acc1);
        acc2 = MFMA16(al2, bh, acc2);
        acc3 = MFMA16(al3, bh, acc3);
        acc0 = MFMA16(ah0, bl, acc0);
        acc1 = MFMA16(ah1, bl, acc1);
        acc2 = MFMA16(ah2, bl, acc2);
        acc3 = MFMA16(ah3, bl, acc3);
    }

    const int row0 = split * 64 + (lane >> 4) * 4;
    const int col  = tb + wave * 16 + (lane & 15);
#pragma unroll
    for (int r = 0; r < 4; ++r) {
        htp[(size_t)(row0 +  0 + r) * TOK + col] = acc0[r];
        htp[(size_t)(row0 + 16 + r) * TOK + col] = acc1[r];
        htp[(size_t)(row0 + 32 + r) * TOK + col] = acc2[r];
        htp[(size_t)(row0 + 48 + r) * TOK + col] = acc3[r];
    }
}

// ---------------- K3: logits -> exp -> z -> weighted dense, all in regs ----
// 16 tokens per block; thread owns 16 tokens x {2 or 1} neurons.
__launch_bounds__(256, 4)
__global__ void k_route(const float* __restrict__ htp, const float* __restrict__ bias,
                        const float* __restrict__ et, const float* __restrict__ imp,
                        float* __restrict__ part) {
    __shared__ float h_l[64][16];
    __shared__ float zw[4][16];
    __shared__ float coef[16];
    __shared__ float impb[16];

    const int tid = threadIdx.x;
    const int blk = blockIdx.x;
    const int tb  = blk * 16;
    const int w   = tid >> 6;

    {   // h = sum of 2 K-split partials + bias -> LDS
        const int k  = tid >> 2;
        const int t4 = (tid & 3) << 2;
        const float4* hp = reinterpret_cast<const float4*>(htp);
        const int col = (tb + t4) >> 2;
        float4 a = hp[(k     ) * 4096 + col];
        float4 b = hp[(k + 64) * 4096 + col];
        float bk = bias[k];
        float4 s;
        s.x = a.x + b.x + bk;
        s.y = a.y + b.y + bk;
        s.z = a.z + b.z + bk;
        s.w = a.w + b.w + bk;
        *reinterpret_cast<float4*>(&h_l[k][t4]) = s;
    }
    if (tid < 16) impb[tid] = imp[tb + tid];
    __syncthreads();

    float acc0[16], acc1[16];
    const int soffs[4] = {0, 512, 1024, 1280};

#pragma unroll 1
    for (int sl = 0; sl < 4; ++sl) {
        const int soff = soffs[sl];
        const bool wide = (sl < 2);   // 512-neuron slices: 2 neurons/thread

#pragma unroll
        for (int t = 0; t < 16; ++t) { acc0[t] = 0.f; acc1[t] = 0.f; }

        if (wide) {
            const float* ep = et + soff + tid * 2;
#pragma unroll 4
            for (int k = 0; k < 64; ++k) {
                const float2 ev = *reinterpret_cast<const float2*>(ep + k * NUSED);
                const float4 h0 = *reinterpret_cast<const float4*>(&h_l[k][0]);
                const float4 h1 = *reinterpret_cast<const float4*>(&h_l[k][4]);
                const float4 h2 = *reinterpret_cast<const float4*>(&h_l[k][8]);
                const float4 h3 = *reinterpret_cast<const float4*>(&h_l[k][12]);
                acc0[0]  = fmaf(h0.x, ev.x, acc0[0]);   acc1[0]  = fmaf(h0.x, ev.y, acc1[0]);
                acc0[1]  = fmaf(h0.y, ev.x, acc0[1]);   acc1[1]  = fmaf(h0.y, ev.y, acc1[1]);
                acc0[2]  = fmaf(h0.z, ev.x, acc0[2]);   acc1[2]  = fmaf(h0.z, ev.y, acc1[2]);
                acc0[3]  = fmaf(h0.w, ev.x, acc0[3]);   acc1[3]  = fmaf(h0.w, ev.y, acc1[3]);
                acc0[4]  = fmaf(h1.x, ev.x, acc0[4]);   acc1[4]  = fmaf(h1.x, ev.y, acc1[4]);
                acc0[5]  = fmaf(h1.y, ev.x, acc0[5]);   acc1[5]  = fmaf(h1.y, ev.y, acc1[5]);
                acc0[6]  = fmaf(h1.z, ev.x, acc0[6]);   acc1[6]  = fmaf(h1.z, ev.y, acc1[6]);
                acc0[7]  = fmaf(h1.w, ev.x, acc0[7]);   acc1[7]  = fmaf(h1.w, ev.y, acc1[7]);
                acc0[8]  = fmaf(h2.x, ev.x, acc0[8]);   acc1[8]  = fmaf(h2.x, ev.y, acc1[8]);
                acc0[9]  = fmaf(h2.y, ev.x, acc0[9]);   acc1[9]  = fmaf(h2.y, ev.y, acc1[9]);
                acc0[10] = fmaf(h2.z, ev.x, acc0[10]);  acc1[10] = fmaf(h2.z, ev.y, acc1[10]);
                acc0[11] = fmaf(h2.w, ev.x, acc0[11]);  acc1[11] = fmaf(h2.w, ev.y, acc1[11]);
                acc0[12] = fmaf(h3.x, ev.x, acc0[12]);  acc1[12] = fmaf(h3.x, ev.y, acc1[12]);
                acc0[13] = fmaf(h3.y, ev.x, acc0[13]);  acc1[13] = fmaf(h3.y, ev.y, acc1[13]);
                acc0[14] = fmaf(h3.z, ev.x, acc0[14]);  acc1[14] = fmaf(h3.z, ev.y, acc1[14]);
                acc0[15] = fmaf(h3.w, ev.x, acc0[15]);  acc1[15] = fmaf(h3.w, ev.y, acc1[15]);
            }
        } else {
            const float* ep = et + soff + tid;
#pragma unroll 4
            for (int k = 0; k < 64; ++k) {
                const float ev = ep[k * NUSED];
                const float4 h0 = *reinterpret_cast<const float4*>(&h_l[k][0]);
                const float4 h1 = *reinterpret_cast<const float4*>(&h_l[k][4]);
                const float4 h2 = *reinterpret_cast<const float4*>(&h_l[k][8]);
                const float4 h3 = *reinterpret_cast<const float4*>(&h_l[k][12]);
                acc0[0]  = fmaf(h0.x, ev, acc0[0]);
                acc0[1]  = fmaf(h0.y, ev, acc0[1]);
                acc0[2]  = fmaf(h0.z, ev, acc0[2]);
                acc0[3]  = fmaf(h0.w, ev, acc0[3]);
                acc0[4]  = fmaf(h1.x, ev, acc0[4]);
                acc0[5]  = fmaf(h1.y, ev, acc0[5]);
                acc0[6]  = fmaf(h1.z, ev, acc0[6]);
                acc0[7]  = fmaf(h1.w, ev, acc0[7]);
                acc0[8]  = fmaf(h2.x, ev, acc0[8]);
                acc0[9]  = fmaf(h2.y, ev, acc0[9]);
                acc0[10] = fmaf(h2.z, ev, acc0[10]);
                acc0[11] = fmaf(h2.w, ev, acc0[11]);
                acc0[12] = fmaf(h3.x, ev, acc0[12]);
                acc0[13] = fmaf(h3.y, ev, acc0[13]);
                acc0[14] = fmaf(h3.z, ev, acc0[14]);
                acc0[15] = fmaf(h3.w, ev, acc0[15]);
            }
        }

        // exp (no max-subtraction: |logit| <= ||h|| ~ 11, safe in fp32)
        float zp[16];
        if (wide) {
#pragma unroll
            for (int t = 0; t < 16; ++t) {
                acc0[t] = __expf(acc0[t]);
                acc1[t] = __expf(acc1[t]);
                zp[t] = acc0[t] + acc1[t];
            }
        } else {
#pragma unroll
            for (int t = 0; t < 16; ++t) {
                acc0[t] = __expf(acc0[t]);
                zp[t] = acc0[t];
            }
        }

        // 64-lane butterfly reduce of the 16 per-token z partials
#pragma unroll
        for (int off = 1; off < 64; off <<= 1) {
#pragma unroll
            for (int t = 0; t < 16; ++t) zp[t] += __shfl_xor(zp[t], off);
        }
        __syncthreads();   // prior slice's zw/coef consumers done
        if ((tid & 63) == 0) {
            *reinterpret_cast<float4*>(&zw[w][0])  = make_float4(zp[0],  zp[1],  zp[2],  zp[3]);
            *reinterpret_cast<float4*>(&zw[w][4])  = make_float4(zp[4],  zp[5],  zp[6],  zp[7]);
            *reinterpret_cast<float4*>(&zw[w][8])  = make_float4(zp[8],  zp[9],  zp[10], zp[11]);
            *reinterpret_cast<float4*>(&zw[w][12]) = make_float4(zp[12], zp[13], zp[14], zp[15]);
        }
        __syncthreads();
        if (tid < 16) {
            float z = zw[0][tid] + zw[1][tid] + zw[2][tid] + zw[3][tid];
            coef[tid] = impb[tid] / z;
        }
        __syncthreads();

        float cf[16];
#pragma unroll
        for (int t = 0; t < 16; t += 4) {
            float4 c4 = *reinterpret_cast<const float4*>(&coef[t]);
            cf[t] = c4.x; cf[t + 1] = c4.y; cf[t + 2] = c4.z; cf[t + 3] = c4.w;
        }
        float d0 = 0.f, d1 = 0.f;
#pragma unroll
        for (int t = 0; t < 16; ++t) {
            d0 = fmaf(cf[t], acc0[t], d0);
            d1 = fmaf(cf[t], acc1[t], d1);
        }
        if (wide) {
            *reinterpret_cast<float2*>(&part[blk * NUSED + soff + tid * 2]) = make_float2(d0, d1);
        } else {
            part[blk * NUSED + soff + tid] = d0;
        }
    }
}

// ---------------- K4a: reduce part 1024 -> 64 rows -------------------------
__launch_bounds__(256)
__global__ void kA(const float* __restrict__ part, float* __restrict__ part2) {
    const int tid = threadIdx.x;
    const int b = blockIdx.x >> 3, g = blockIdx.x & 7;
    const int base = (b * 128 + g * 16) * NUSED;
#pragma unroll
    for (int i = 0; i < 6; ++i) {
        int n = tid + 256 * i;
        float s = 0.f;
#pragma unroll
        for (int r = 0; r < 16; ++r) s += part[base + r * NUSED + n];
        part2[(b * 8 + g) * NUSED + n] = s;
    }
}

// ---------------- K4b: final reduce + top-k sparsify + output --------------
__launch_bounds__(256)
__global__ void kB(const float* __restrict__ part2, float* __restrict__ out) {
    __shared__ float dens[NUSED];
    __shared__ float s_v[4][8];
    __shared__ int   s_n[4][8];
    const int tid = threadIdx.x;
    const int b = blockIdx.x;

#pragma unroll
    for (int i = 0; i < 6; ++i) {
        int n = tid + 256 * i;
        float s = 0.f;
#pragma unroll
        for (int g = 0; g < 8; ++g) s += part2[(b * 8 + g) * NUSED + n];
        dens[n] = s;
    }
    for (int i = tid; i < 1792; i += 256) out[b * 1792 + i] = 0.f;
    __syncthreads();

    const int w = tid >> 6, lane = tid & 63;
    const int soffs[4] = {0, 512, 1024, 1280};
    const int ssz[4]   = {512, 512, 256, 256};
    const int kks[4]   = {8, 8, 4, 6};
    const int ooffs[4] = {0, 512, 1024, 1536};
    const int Sn = ssz[w], soff = soffs[w], kk = kks[w];
    const int nslots = Sn >> 6;

    float v[8];
#pragma unroll
    for (int i = 0; i < 8; ++i)
        v[i] = (i < nslots) ? dens[soff + lane + 64 * i] : -1e30f;

    unsigned rm = 0;
    float ssum = 0.f;
    for (int it = 0; it < kk; ++it) {
        float bv = -1e30f;
        int bn = 0x7fffffff;
#pragma unroll
        for (int i = 0; i < 8; ++i) {
            bool valid = (i < nslots) && !((rm >> i) & 1u);
            if (valid && v[i] > bv) { bv = v[i]; bn = lane + 64 * i; }
        }
#pragma unroll
        for (int off = 32; off; off >>= 1) {
            float ov = __shfl_xor(bv, off);
            int   on = __shfl_xor(bn, off);
            if (ov > bv || (ov == bv && on < bn)) { bv = ov; bn = on; }
        }
        ssum += bv;
        if ((bn & 63) == lane) rm |= 1u << (bn >> 6);
        if (lane == 0) { s_v[w][it] = bv; s_n[w][it] = bn; }
    }
    const float inv = 1.f / (ssum + 1e-8f);
    if (lane < kk) {
        int n = s_n[w][lane];
        float val = s_v[w][lane] * inv;
        out[b * 1792 + ooffs[w] + n] = val;
        if (w == 2) out[b * 1792 + 1280 + n] = val;  // rk = rq
    }
}

extern "C" void kernel_launch(void* const* d_in, const int* in_sizes, int n_in,
                              void* d_out, int out_size, void* d_ws, size_t ws_size,
                              hipStream_t stream) {
    const float* x    = (const float*)d_in[0];
    const float* imp  = (const float*)d_in[1];
    const float* W    = (const float*)d_in[2];
    const float* bias = (const float*)d_in[3];
    const float* emb  = (const float*)d_in[4];
    float* out = (float*)d_out;
    float* ws  = (float*)d_ws;

    float* et    = ws + WS_EMB;
    float* htp   = ws + WS_HT;
    float* part  = ws + WS_PART;
    float* part2 = ws + WS_PART2;
    short* wfrag = (short*)(ws + WS_WF);

    k_wsplit<<<64, 256, 0, stream>>>(W, wfrag);
    k_embnorm<<<NUSED / 4, 256, 0, stream>>>(emb, et);
    k_gemm1<<<512, 256, 0, stream>>>(x, wfrag, htp);
    k_route<<<1024, 256, 0, stream>>>(htp, bias, et, imp, part);
    kA<<<64, 256, 0, stream>>>(part, part2);
    kB<<<8, 256, 0, stream>>>(part2, out);
}

// Round 5
// 92.125 us; speedup vs baseline: 2.5169x; 1.3499x over previous
//
#include <hip/hip_runtime.h>
#include <hip/hip_bf16.h>
#include <hip/hip_fp16.h>

#define B_    8
#define S_    2048
#define D_    2048
#define DS_   64
#define NUSED 1536
#define TOK   16384  // B_*S_

typedef __attribute__((ext_vector_type(8))) short bf16x8;
typedef __attribute__((ext_vector_type(4))) float f32x4;

// ws layout (float offsets)
static constexpr int WS_ETF   = 0;          // etfrag: 196608 shorts (98304 f)
static constexpr int WS_HT    = 98304;      // htp[2][64][16384] f32
static constexpr int WS_HF    = 2195456;    // hfrag: 2097152 shorts
static constexpr int WS_PART  = 3244032;    // part[1024][1536]
static constexpr int WS_PART2 = 4816896;    // part2[64][1536]
static constexpr int WS_WF    = 4915200;    // wfrag: 262144 shorts

__device__ inline short bf_hi(float f, float& rhi) {
    __hip_bfloat16 h = __float2bfloat16(f);
    rhi = __bfloat162float(h);
    return __builtin_bit_cast(short, h);
}
__device__ inline short bf_of(float f) {
    __hip_bfloat16 h = __float2bfloat16(f);
    return __builtin_bit_cast(short, h);
}
__device__ inline int sliceOfTile(int tile) {
    return tile < 32 ? 0 : tile < 64 ? 1 : tile < 80 ? 2 : 3;
}

// ---------------- K0: W -> fragment-ready bf16 hi/lo (for gemm1) -----------
__launch_bounds__(256)
__global__ void k_wsplit(const float* __restrict__ W, short* __restrict__ wfrag) {
    const int t = threadIdx.x, kstep = blockIdx.x;
    const int msub = t >> 6, lane = t & 63;
    const int m = msub * 16 + (lane & 15);
    const float* wp = W + m * D_ + kstep * 32 + (lane >> 4) * 8;
    float4 a = *reinterpret_cast<const float4*>(wp);
    float4 b = *reinterpret_cast<const float4*>(wp + 4);
    float f[8] = {a.x, a.y, a.z, a.w, b.x, b.y, b.z, b.w};
    bf16x8 hi, lo;
#pragma unroll
    for (int j = 0; j < 8; ++j) {
        float r;
        hi[j] = bf_hi(f[j], r);
        lo[j] = bf_of(f[j] - r);
    }
    short* dst = wfrag + (((kstep << 2) | msub) * 64 + lane) * 16;
    *reinterpret_cast<bf16x8*>(dst)     = hi;
    *reinterpret_cast<bf16x8*>(dst + 8) = lo;
}

// ---------------- K1: normalize emb + pack A-fragments (hi/lo), fused ------
// block = 1 tile (16 neurons), 128 threads = {kh 2} x {lane 64}
// etfrag[tile 96][kh 2][lane 64][8hi|8lo]; A row = lane&15 (neuron),
// k = kh*32 + (lane>>4)*8 + j
__launch_bounds__(128)
__global__ void k_embpack(const float* __restrict__ emb, short* __restrict__ etfrag) {
    __shared__ float red[16][8];
    __shared__ float rn[16];
    const int tid = threadIdx.x;
    const int kh = tid >> 6, lane = tid & 63;
    const int tile = blockIdx.x;
    const int nl = lane & 15;
    const int n = tile * 16 + nl;
    const int kb = kh * 32 + (lane >> 4) * 8;
    const float* ep = emb + n * DS_ + kb;
    float4 a = *reinterpret_cast<const float4*>(ep);
    float4 b = *reinterpret_cast<const float4*>(ep + 4);
    float f[8] = {a.x, a.y, a.z, a.w, b.x, b.y, b.z, b.w};
    float ss = 0.f;
#pragma unroll
    for (int j = 0; j < 8; ++j) ss += f[j] * f[j];
    red[nl][kh * 4 + (lane >> 4)] = ss;
    __syncthreads();
    if (tid < 16) {
        float s = 0.f;
#pragma unroll
        for (int j = 0; j < 8; ++j) s += red[tid][j];
        rn[tid] = 1.0f / sqrtf(s);
    }
    __syncthreads();
    const float r0 = rn[nl];
    bf16x8 hi, lo;
#pragma unroll
    for (int j = 0; j < 8; ++j) {
        float v = f[j] * r0, r;
        hi[j] = bf_hi(v, r);
        lo[j] = bf_of(v - r);
    }
    short* dst = etfrag + (size_t)((tile * 2 + kh) * 64 + lane) * 16;
    *reinterpret_cast<bf16x8*>(dst)     = hi;
    *reinterpret_cast<bf16x8*>(dst + 8) = lo;
}

// ---------------- K2: h^T = W @ x^T via split-bf16 MFMA (K-split 2) --------
#define MFMA16(A, Bv, C) __builtin_amdgcn_mfma_f32_16x16x32_bf16(A, Bv, C, 0, 0, 0)

__launch_bounds__(256, 2)
__global__ void k_gemm1(const float* __restrict__ x, const short* __restrict__ wfrag,
                        float* __restrict__ htp) {
    const int tid   = threadIdx.x;
    const int split = blockIdx.x & 1;
    const int tb    = (blockIdx.x >> 1) * 64;
    const int wave  = tid >> 6, lane = tid & 63;
    const int tok   = tb + wave * 16 + (lane & 15);

    const float* xp = x + (size_t)tok * D_ + split * 1024 + (lane >> 4) * 8;
    const short* wp = wfrag + split * 32 * 4096 + lane * 16;

    f32x4 acc0 = {0.f, 0.f, 0.f, 0.f};
    f32x4 acc1 = acc0, acc2 = acc0, acc3 = acc0;

    float4 xa = *reinterpret_cast<const float4*>(xp);
    float4 xb = *reinterpret_cast<const float4*>(xp + 4);

#pragma unroll 2
    for (int ks = 0; ks < 32; ++ks) {
        const short* wk = wp + ks * 4096;
        bf16x8 ah0 = *reinterpret_cast<const bf16x8*>(wk);
        bf16x8 al0 = *reinterpret_cast<const bf16x8*>(wk + 8);
        bf16x8 ah1 = *reinterpret_cast<const bf16x8*>(wk + 1024);
        bf16x8 al1 = *reinterpret_cast<const bf16x8*>(wk + 1032);
        bf16x8 ah2 = *reinterpret_cast<const bf16x8*>(wk + 2048);
        bf16x8 al2 = *reinterpret_cast<const bf16x8*>(wk + 2056);
        bf16x8 ah3 = *reinterpret_cast<const bf16x8*>(wk + 3072);
        bf16x8 al3 = *reinterpret_cast<const bf16x8*>(wk + 3080);

        float xf[8] = {xa.x, xa.y, xa.z, xa.w, xb.x, xb.y, xb.z, xb.w};
        bf16x8 bh, bl;
#pragma unroll
        for (int j = 0; j < 8; ++j) {
            float r;
            bh[j] = bf_hi(xf[j], r);
            bl[j] = bf_of(xf[j] - r);
        }
        if (ks < 31) {  // prefetch next x slab while MFMAs run
            xa = *reinterpret_cast<const float4*>(xp + (ks + 1) * 32);
            xb = *reinterpret_cast<const float4*>(xp + (ks + 1) * 32 + 4);
        }
        acc0 = MFMA16(ah0, bh, acc0);
        acc1 = MFMA16(ah1, bh, acc1);
        acc2 = MFMA16(ah2, bh, acc2);
        acc3 = MFMA16(ah3, bh, acc3);
        acc0 = MFMA16(al0, bh, acc0);
        acc1 = MFMA16(al1, bh, acc1);
        acc2 = MFMA16(al2, bh, acc2);
        acc3 = MFMA16(al3, bh, acc3);
        acc0 = MFMA16(ah0, bl, acc0);
        acc1 = MFMA16(ah1, bl, acc1);
        acc2 = MFMA16(ah2, bl, acc2);
        acc3 = MFMA16(ah3, bl, acc3);
    }

    const int row0 = split * 64 + (lane >> 4) * 4;
    const int col  = tb + wave * 16 + (lane & 15);
#pragma unroll
    for (int r = 0; r < 4; ++r) {
        htp[(size_t)(row0 +  0 + r) * TOK + col] = acc0[r];
        htp[(size_t)(row0 + 16 + r) * TOK + col] = acc1[r];
        htp[(size_t)(row0 + 32 + r) * TOK + col] = acc2[r];
        htp[(size_t)(row0 + 48 + r) * TOK + col] = acc3[r];
    }
}

// ---------------- K2b: sum K-split partials + bias -> h B-fragments --------
// hfrag[tt 1024][kh 2][lane 64][8hi|8lo]; B col = lane&15 (token),
// k = kh*32 + (lane>>4)*8 + j  (matches etfrag map)
__launch_bounds__(256)
__global__ void k_hfix(const float* __restrict__ htp, const float* __restrict__ bias,
                       short* __restrict__ hfrag) {
    const int idx = blockIdx.x * 256 + threadIdx.x;   // 1024*2*64 = 131072
    const int tt = idx >> 7, rem = idx & 127;
    const int kh = rem >> 6, lane = rem & 63;
    const int t = tt * 16 + (lane & 15);
    const int kb = kh * 32 + (lane >> 4) * 8;
    bf16x8 hi, lo;
#pragma unroll
    for (int j = 0; j < 8; ++j) {
        const int k = kb + j;
        float v = htp[(size_t)k * TOK + t] + htp[(size_t)(k + 64) * TOK + t] + bias[k];
        float r;
        hi[j] = bf_hi(v, r);
        lo[j] = bf_of(v - r);
    }
    short* dst = hfrag + (size_t)((tt * 2 + kh) * 64 + lane) * 16;
    *reinterpret_cast<bf16x8*>(dst)     = hi;
    *reinterpret_cast<bf16x8*>(dst + 8) = lo;
}

// ---------------- K3: MFMA routing, p fully in fp32 registers --------------
// Block = 16 tokens (tile tt). 8 waves x 12 neuron-tiles each.
// Pass1: logits->p(regs), z. Pass2: scale by coef, butterfly over token lanes.
__launch_bounds__(512, 2)
__global__ void k_route2(const short* __restrict__ hfrag, const short* __restrict__ etfrag,
                         const float* __restrict__ imp, float* __restrict__ part) {
    __shared__ float zw[8][2][16];
    __shared__ float coef[4][16];
    __shared__ float impb[16];

    const int tid = threadIdx.x;
    const int w = tid >> 6, lane = tid & 63;
    const int tt = blockIdx.x;
    const int tk = lane & 15, g = lane >> 4;

    // B fragments (h) hi/lo for both k-halves
    const short* hp = hfrag + (size_t)(tt * 2) * 1024 + lane * 16;
    bf16x8 bh0 = *reinterpret_cast<const bf16x8*>(hp);
    bf16x8 bl0 = *reinterpret_cast<const bf16x8*>(hp + 8);
    bf16x8 bh1 = *reinterpret_cast<const bf16x8*>(hp + 1024);
    bf16x8 bl1 = *reinterpret_cast<const bf16x8*>(hp + 1032);

    if (tid < 16) impb[tid] = imp[tt * 16 + tid];

    const int t0 = w * 12;
    const int sA = sliceOfTile(t0);
    const int sB = sliceOfTile(t0 + 11);
    float zacc0 = 0.f, zacc1 = 0.f;
    float p[12][4];   // fp32 p, statically indexed (full unroll)

    const short* ep = etfrag + (size_t)t0 * 2048 + lane * 16;
#pragma unroll
    for (int ti = 0; ti < 12; ++ti) {
        const short* cp = ep + (size_t)ti * 2048;
        bf16x8 ah0 = *reinterpret_cast<const bf16x8*>(cp);
        bf16x8 al0 = *reinterpret_cast<const bf16x8*>(cp + 8);
        bf16x8 ah1 = *reinterpret_cast<const bf16x8*>(cp + 1024);
        bf16x8 al1 = *reinterpret_cast<const bf16x8*>(cp + 1032);
        f32x4 a0 = {0.f, 0.f, 0.f, 0.f};
        f32x4 a1 = {0.f, 0.f, 0.f, 0.f};
        a0 = MFMA16(ah0, bh0, a0);
        a1 = MFMA16(ah1, bh1, a1);
        a0 = MFMA16(al0, bh0, a0);
        a1 = MFMA16(al1, bh1, a1);
        a0 = MFMA16(ah0, bl0, a0);
        a1 = MFMA16(ah1, bl1, a1);
        const float p0 = __expf(a0[0] + a1[0]);
        const float p1 = __expf(a0[1] + a1[1]);
        const float p2 = __expf(a0[2] + a1[2]);
        const float p3 = __expf(a0[3] + a1[3]);
        p[ti][0] = p0; p[ti][1] = p1; p[ti][2] = p2; p[ti][3] = p3;
        const float zs = (p0 + p1) + (p2 + p3);
        if (sliceOfTile(t0 + ti) == sA) zacc0 += zs; else zacc1 += zs;
    }

    // z: reduce across the 4 row-groups (lanes differing in bits 4,5)
    zacc0 += __shfl_xor(zacc0, 16); zacc0 += __shfl_xor(zacc0, 32);
    zacc1 += __shfl_xor(zacc1, 16); zacc1 += __shfl_xor(zacc1, 32);
    if (lane < 16) { zw[w][0][lane] = zacc0; zw[w][1][lane] = zacc1; }
    __syncthreads();

    if (tid < 64) {
        const int s = tid >> 4, k2 = tid & 15;
        float z = 0.f;
#pragma unroll
        for (int w2 = 0; w2 < 8; ++w2) {
            const int a = sliceOfTile(w2 * 12);
            const int b = sliceOfTile(w2 * 12 + 11);
            if (a == s) z += zw[w2][0][k2];
            if (b == s && b != a) z += zw[w2][1][k2];
        }
        coef[s][k2] = impb[k2] / z;
    }
    __syncthreads();

    // pass 2: dense[n] = sum_t coef[t] * p[t,n]; tokens live across tk lanes
    const float cA = coef[sA][tk];
    const float cB = coef[sB][tk];
    float* pout = part + (size_t)tt * NUSED;
#pragma unroll
    for (int ti = 0; ti < 12; ++ti) {
        const float c = (sliceOfTile(t0 + ti) == sA) ? cA : cB;
        float v0 = p[ti][0] * c, v1 = p[ti][1] * c, v2 = p[ti][2] * c, v3 = p[ti][3] * c;
#pragma unroll
        for (int st = 1; st < 16; st <<= 1) {
            v0 += __shfl_xor(v0, st);
            v1 += __shfl_xor(v1, st);
            v2 += __shfl_xor(v2, st);
            v3 += __shfl_xor(v3, st);
        }
        if (tk == 0)
            *reinterpret_cast<float4*>(&pout[(t0 + ti) * 16 + g * 4]) =
                make_float4(v0, v1, v2, v3);
    }
}

// ---------------- K4a: reduce part 1024 -> 64 rows -------------------------
__launch_bounds__(256)
__global__ void kA(const float* __restrict__ part, float* __restrict__ part2) {
    const int tid = threadIdx.x;
    const int b = blockIdx.x >> 3, g = blockIdx.x & 7;
    const int base = (b * 128 + g * 16) * NUSED;
#pragma unroll
    for (int i = 0; i < 6; ++i) {
        int n = tid + 256 * i;
        float s = 0.f;
#pragma unroll
        for (int r = 0; r < 16; ++r) s += part[base + r * NUSED + n];
        part2[(b * 8 + g) * NUSED + n] = s;
    }
}

// ---------------- K4b: final reduce + top-k sparsify + output --------------
__launch_bounds__(256)
__global__ void kB(const float* __restrict__ part2, float* __restrict__ out) {
    __shared__ float dens[NUSED];
    __shared__ float s_v[4][8];
    __shared__ int   s_n[4][8];
    const int tid = threadIdx.x;
    const int b = blockIdx.x;

#pragma unroll
    for (int i = 0; i < 6; ++i) {
        int n = tid + 256 * i;
        float s = 0.f;
#pragma unroll
        for (int g = 0; g < 8; ++g) s += part2[(b * 8 + g) * NUSED + n];
        dens[n] = s;
    }
    for (int i = tid; i < 1792; i += 256) out[b * 1792 + i] = 0.f;
    __syncthreads();

    const int w = tid >> 6, lane = tid & 63;
    const int soffs[4] = {0, 512, 1024, 1280};
    const int ssz[4]   = {512, 512, 256, 256};
    const int kks[4]   = {8, 8, 4, 6};
    const int ooffs[4] = {0, 512, 1024, 1536};
    const int Sn = ssz[w], soff = soffs[w], kk = kks[w];
    const int nslots = Sn >> 6;

    float v[8];
#pragma unroll
    for (int i = 0; i < 8; ++i)
        v[i] = (i < nslots) ? dens[soff + lane + 64 * i] : -1e30f;

    unsigned rm = 0;
    float ssum = 0.f;
    for (int it = 0; it < kk; ++it) {
        float bv = -1e30f;
        int bn = 0x7fffffff;
#pragma unroll
        for (int i = 0; i < 8; ++i) {
            bool valid = (i < nslots) && !((rm >> i) & 1u);
            if (valid && v[i] > bv) { bv = v[i]; bn = lane + 64 * i; }
        }
#pragma unroll
        for (int off = 32; off; off >>= 1) {
            float ov = __shfl_xor(bv, off);
            int   on = __shfl_xor(bn, off);
            if (ov > bv || (ov == bv && on < bn)) { bv = ov; bn = on; }
        }
        ssum += bv;
        if ((bn & 63) == lane) rm |= 1u << (bn >> 6);
        if (lane == 0) { s_v[w][it] = bv; s_n[w][it] = bn; }
    }
    const float inv = 1.f / (ssum + 1e-8f);
    if (lane < kk) {
        int n = s_n[w][lane];
        float val = s_v[w][lane] * inv;
        out[b * 1792 + ooffs[w] + n] = val;
        if (w == 2) out[b * 1792 + 1280 + n] = val;  // rk = rq
    }
}

extern "C" void kernel_launch(void* const* d_in, const int* in_sizes, int n_in,
                              void* d_out, int out_size, void* d_ws, size_t ws_size,
                              hipStream_t stream) {
    const float* x    = (const float*)d_in[0];
    const float* imp  = (const float*)d_in[1];
    const float* W    = (const float*)d_in[2];
    const float* bias = (const float*)d_in[3];
    const float* emb  = (const float*)d_in[4];
    float* out = (float*)d_out;
    float* ws  = (float*)d_ws;

    short* etfrag = (short*)(ws + WS_ETF);
    float* htp    = ws + WS_HT;
    short* hfrag  = (short*)(ws + WS_HF);
    float* part   = ws + WS_PART;
    float* part2  = ws + WS_PART2;
    short* wfrag  = (short*)(ws + WS_WF);

    k_embpack<<<96, 128, 0, stream>>>(emb, etfrag);
    k_wsplit<<<64, 256, 0, stream>>>(W, wfrag);
    k_gemm1<<<512, 256, 0, stream>>>(x, wfrag, htp);
    k_hfix<<<512, 256, 0, stream>>>(htp, bias, hfrag);
    k_route2<<<1024, 512, 0, stream>>>(hfrag, etfrag, imp, part);
    kA<<<64, 256, 0, stream>>>(part, part2);
    kB<<<8, 256, 0, stream>>>(part2, out);
}

// Round 6
// 87.422 us; speedup vs baseline: 2.6523x; 1.0538x over previous
//
#include <hip/hip_runtime.h>
#include <hip/hip_bf16.h>
#include <hip/hip_fp16.h>

#define B_    8
#define S_    2048
#define D_    2048
#define DS_   64
#define NUSED 1536
#define TOK   16384  // B_*S_

typedef __attribute__((ext_vector_type(8))) short bf16x8;
typedef __attribute__((ext_vector_type(4))) float f32x4;

// ws layout (float offsets)
static constexpr int WS_ETF   = 0;          // etfrag: 196608 shorts (98304 f)
static constexpr int WS_HT    = 98304;      // htp[2][64][16384] f32
static constexpr int WS_HF    = 2195456;    // hfrag: 2097152 shorts
static constexpr int WS_PART  = 3244032;    // part[1024][1536]
static constexpr int WS_PART2 = 4816896;    // part2[64][1536]
static constexpr int WS_WF    = 4915200;    // wfrag2: 262144 shorts

typedef __attribute__((address_space(1))) const void g_void;
typedef __attribute__((address_space(3))) void l_void;

__device__ inline short bf_hi(float f, float& rhi) {
    __hip_bfloat16 h = __float2bfloat16(f);
    rhi = __bfloat162float(h);
    return __builtin_bit_cast(short, h);
}
__device__ inline short bf_of(float f) {
    __hip_bfloat16 h = __float2bfloat16(f);
    return __builtin_bit_cast(short, h);
}
__device__ inline int sliceOfTile(int tile) {
    return tile < 32 ? 0 : tile < 64 ? 1 : tile < 80 ? 2 : 3;
}

// ---------------- K0: W -> LDS-stageable bf16 hi/lo chunks -----------------
// wfrag2[kstep 64][msub 4][h 2][lane 64][8 shorts]
// W row m = msub*16 + (lane&15), k = kstep*32 + (lane>>4)*8 + j
__launch_bounds__(256)
__global__ void k_wsplit(const float* __restrict__ W, short* __restrict__ wfrag) {
    const int t = threadIdx.x, kstep = blockIdx.x;
    const int msub = t >> 6, lane = t & 63;
    const int m = msub * 16 + (lane & 15);
    const float* wp = W + m * D_ + kstep * 32 + (lane >> 4) * 8;
    float4 a = *reinterpret_cast<const float4*>(wp);
    float4 b = *reinterpret_cast<const float4*>(wp + 4);
    float f[8] = {a.x, a.y, a.z, a.w, b.x, b.y, b.z, b.w};
    bf16x8 hi, lo;
#pragma unroll
    for (int j = 0; j < 8; ++j) {
        float r;
        hi[j] = bf_hi(f[j], r);
        lo[j] = bf_of(f[j] - r);
    }
    short* base = wfrag + (size_t)(kstep * 4 + msub) * 1024;
    *reinterpret_cast<bf16x8*>(base + lane * 8)       = hi;
    *reinterpret_cast<bf16x8*>(base + 512 + lane * 8) = lo;
}

// ---------------- K1: normalize emb + pack A-fragments (hi/lo), fused ------
// block = 1 tile (16 neurons), 128 threads = {kh 2} x {lane 64}
// etfrag[tile 96][kh 2][lane 64][8hi|8lo]; A row = lane&15 (neuron),
// k = kh*32 + (lane>>4)*8 + j
__launch_bounds__(128)
__global__ void k_embpack(const float* __restrict__ emb, short* __restrict__ etfrag) {
    __shared__ float red[16][8];
    __shared__ float rn[16];
    const int tid = threadIdx.x;
    const int kh = tid >> 6, lane = tid & 63;
    const int tile = blockIdx.x;
    const int nl = lane & 15;
    const int n = tile * 16 + nl;
    const int kb = kh * 32 + (lane >> 4) * 8;
    const float* ep = emb + n * DS_ + kb;
    float4 a = *reinterpret_cast<const float4*>(ep);
    float4 b = *reinterpret_cast<const float4*>(ep + 4);
    float f[8] = {a.x, a.y, a.z, a.w, b.x, b.y, b.z, b.w};
    float ss = 0.f;
#pragma unroll
    for (int j = 0; j < 8; ++j) ss += f[j] * f[j];
    red[nl][kh * 4 + (lane >> 4)] = ss;
    __syncthreads();
    if (tid < 16) {
        float s = 0.f;
#pragma unroll
        for (int j = 0; j < 8; ++j) s += red[tid][j];
        rn[tid] = 1.0f / sqrtf(s);
    }
    __syncthreads();
    const float r0 = rn[nl];
    bf16x8 hi, lo;
#pragma unroll
    for (int j = 0; j < 8; ++j) {
        float v = f[j] * r0, r;
        hi[j] = bf_hi(v, r);
        lo[j] = bf_of(v - r);
    }
    short* dst = etfrag + (size_t)((tile * 2 + kh) * 64 + lane) * 16;
    *reinterpret_cast<bf16x8*>(dst)     = hi;
    *reinterpret_cast<bf16x8*>(dst + 8) = lo;
}

// ---------------- K2: h^T = W @ x^T, split-bf16 MFMA, LDS-shared W ---------
#define MFMA16(A, Bv, C) __builtin_amdgcn_mfma_f32_16x16x32_bf16(A, Bv, C, 0, 0, 0)

__launch_bounds__(256, 2)
__global__ void k_gemm1(const float* __restrict__ x, const short* __restrict__ wfrag,
                        float* __restrict__ htp) {
    __shared__ short wlds[2][4096];   // per-ks W slab: [msub 4][hi|lo][lane 64][8]

    const int tid   = threadIdx.x;
    const int split = blockIdx.x & 1;
    const int tb    = (blockIdx.x >> 1) * 64;
    const int wave  = tid >> 6, lane = tid & 63;
    const int tok   = tb + wave * 16 + (lane & 15);

    const float* xp   = x + (size_t)tok * D_ + split * 1024 + (lane >> 4) * 8;
    const short* wsrc = wfrag + (size_t)(split * 32) * 4096;

    f32x4 acc0 = {0.f, 0.f, 0.f, 0.f};
    f32x4 acc1 = acc0, acc2 = acc0, acc3 = acc0;

    // prologue: stage ks=0 W slab, load ks=0 x slab
    __builtin_amdgcn_global_load_lds((g_void*)(wsrc + tid * 8),
                                     (l_void*)(&wlds[0][tid * 8]), 16, 0, 0);
    __builtin_amdgcn_global_load_lds((g_void*)(wsrc + 2048 + tid * 8),
                                     (l_void*)(&wlds[0][2048 + tid * 8]), 16, 0, 0);
    float4 xa = *reinterpret_cast<const float4*>(xp);
    float4 xb = *reinterpret_cast<const float4*>(xp + 4);

    for (int ks = 0; ks < 32; ++ks) {
        __syncthreads();   // drains stage(ks) + x(ks); publishes wlds[ks&1]
        const int buf = ks & 1;
        if (ks < 31) {     // stage next W slab into the other buffer
            const short* ns = wsrc + (size_t)(ks + 1) * 4096;
            __builtin_amdgcn_global_load_lds((g_void*)(ns + tid * 8),
                                             (l_void*)(&wlds[buf ^ 1][tid * 8]), 16, 0, 0);
            __builtin_amdgcn_global_load_lds((g_void*)(ns + 2048 + tid * 8),
                                             (l_void*)(&wlds[buf ^ 1][2048 + tid * 8]), 16, 0, 0);
        }

        float xf[8] = {xa.x, xa.y, xa.z, xa.w, xb.x, xb.y, xb.z, xb.w};
        bf16x8 bh, bl;
#pragma unroll
        for (int j = 0; j < 8; ++j) {
            float r;
            bh[j] = bf_hi(xf[j], r);
            bl[j] = bf_of(xf[j] - r);
        }
        if (ks < 31) {  // prefetch next x slab while MFMAs run
            xa = *reinterpret_cast<const float4*>(xp + (ks + 1) * 32);
            xb = *reinterpret_cast<const float4*>(xp + (ks + 1) * 32 + 4);
        }

        const short* wl = &wlds[buf][0];
        bf16x8 ah0 = *reinterpret_cast<const bf16x8*>(wl +    0 + lane * 8);
        bf16x8 al0 = *reinterpret_cast<const bf16x8*>(wl +  512 + lane * 8);
        bf16x8 ah1 = *reinterpret_cast<const bf16x8*>(wl + 1024 + lane * 8);
        bf16x8 al1 = *reinterpret_cast<const bf16x8*>(wl + 1536 + lane * 8);
        bf16x8 ah2 = *reinterpret_cast<const bf16x8*>(wl + 2048 + lane * 8);
        bf16x8 al2 = *reinterpret_cast<const bf16x8*>(wl + 2560 + lane * 8);
        bf16x8 ah3 = *reinterpret_cast<const bf16x8*>(wl + 3072 + lane * 8);
        bf16x8 al3 = *reinterpret_cast<const bf16x8*>(wl + 3584 + lane * 8);

        acc0 = MFMA16(ah0, bh, acc0);
        acc1 = MFMA16(ah1, bh, acc1);
        acc2 = MFMA16(ah2, bh, acc2);
        acc3 = MFMA16(ah3, bh, acc3);
        acc0 = MFMA16(al0, bh, acc0);
        acc1 = MFMA16(al1, bh, acc1);
        acc2 = MFMA16(al2, bh, acc2);
        acc3 = MFMA16(al3, bh, acc3);
        acc0 = MFMA16(ah0, bl, acc0);
        acc1 = MFMA16(ah1, bl, acc1);
        acc2 = MFMA16(ah2, bl, acc2);
        acc3 = MFMA16(ah3, bl, acc3);
    }

    const int row0 = split * 64 + (lane >> 4) * 4;
    const int col  = tb + wave * 16 + (lane & 15);
#pragma unroll
    for (int r = 0; r < 4; ++r) {
        htp[(size_t)(row0 +  0 + r) * TOK + col] = acc0[r];
        htp[(size_t)(row0 + 16 + r) * TOK + col] = acc1[r];
        htp[(size_t)(row0 + 32 + r) * TOK + col] = acc2[r];
        htp[(size_t)(row0 + 48 + r) * TOK + col] = acc3[r];
    }
}

// ---------------- K2b: sum K-split partials + bias -> h B-fragments --------
// hfrag[tt 1024][kh 2][lane 64][8hi|8lo]; B col = lane&15 (token),
// k = kh*32 + (lane>>4)*8 + j  (matches etfrag map)
__launch_bounds__(256)
__global__ void k_hfix(const float* __restrict__ htp, const float* __restrict__ bias,
                       short* __restrict__ hfrag) {
    const int idx = blockIdx.x * 256 + threadIdx.x;   // 1024*2*64 = 131072
    const int tt = idx >> 7, rem = idx & 127;
    const int kh = rem >> 6, lane = rem & 63;
    const int t = tt * 16 + (lane & 15);
    const int kb = kh * 32 + (lane >> 4) * 8;
    bf16x8 hi, lo;
#pragma unroll
    for (int j = 0; j < 8; ++j) {
        const int k = kb + j;
        float v = htp[(size_t)k * TOK + t] + htp[(size_t)(k + 64) * TOK + t] + bias[k];
        float r;
        hi[j] = bf_hi(v, r);
        lo[j] = bf_of(v - r);
    }
    short* dst = hfrag + (size_t)((tt * 2 + kh) * 64 + lane) * 16;
    *reinterpret_cast<bf16x8*>(dst)     = hi;
    *reinterpret_cast<bf16x8*>(dst + 8) = lo;
}

// ---------------- K3: MFMA routing, p fully in fp32 registers --------------
// Block = 16 tokens (tile tt). 8 waves x 12 neuron-tiles each.
// Pass1: logits->p(regs), z. Pass2: scale by coef, butterfly over token lanes.
__launch_bounds__(512, 2)
__global__ void k_route2(const short* __restrict__ hfrag, const short* __restrict__ etfrag,
                         const float* __restrict__ imp, float* __restrict__ part) {
    __shared__ float zw[8][2][16];
    __shared__ float coef[4][16];
    __shared__ float impb[16];

    const int tid = threadIdx.x;
    const int w = tid >> 6, lane = tid & 63;
    const int tt = blockIdx.x;
    const int tk = lane & 15, g = lane >> 4;

    // B fragments (h) hi/lo for both k-halves
    const short* hp = hfrag + (size_t)(tt * 2) * 1024 + lane * 16;
    bf16x8 bh0 = *reinterpret_cast<const bf16x8*>(hp);
    bf16x8 bl0 = *reinterpret_cast<const bf16x8*>(hp + 8);
    bf16x8 bh1 = *reinterpret_cast<const bf16x8*>(hp + 1024);
    bf16x8 bl1 = *reinterpret_cast<const bf16x8*>(hp + 1032);

    if (tid < 16) impb[tid] = imp[tt * 16 + tid];

    const int t0 = w * 12;
    const int sA = sliceOfTile(t0);
    const int sB = sliceOfTile(t0 + 11);
    float zacc0 = 0.f, zacc1 = 0.f;
    float p[12][4];   // fp32 p, statically indexed (full unroll)

    const short* ep = etfrag + (size_t)t0 * 2048 + lane * 16;
#pragma unroll
    for (int ti = 0; ti < 12; ++ti) {
        const short* cp = ep + (size_t)ti * 2048;
        bf16x8 ah0 = *reinterpret_cast<const bf16x8*>(cp);
        bf16x8 al0 = *reinterpret_cast<const bf16x8*>(cp + 8);
        bf16x8 ah1 = *reinterpret_cast<const bf16x8*>(cp + 1024);
        bf16x8 al1 = *reinterpret_cast<const bf16x8*>(cp + 1032);
        f32x4 a0 = {0.f, 0.f, 0.f, 0.f};
        f32x4 a1 = {0.f, 0.f, 0.f, 0.f};
        a0 = MFMA16(ah0, bh0, a0);
        a1 = MFMA16(ah1, bh1, a1);
        a0 = MFMA16(al0, bh0, a0);
        a1 = MFMA16(al1, bh1, a1);
        a0 = MFMA16(ah0, bl0, a0);
        a1 = MFMA16(ah1, bl1, a1);
        const float p0 = __expf(a0[0] + a1[0]);
        const float p1 = __expf(a0[1] + a1[1]);
        const float p2 = __expf(a0[2] + a1[2]);
        const float p3 = __expf(a0[3] + a1[3]);
        p[ti][0] = p0; p[ti][1] = p1; p[ti][2] = p2; p[ti][3] = p3;
        const float zs = (p0 + p1) + (p2 + p3);
        if (sliceOfTile(t0 + ti) == sA) zacc0 += zs; else zacc1 += zs;
    }

    // z: reduce across the 4 row-groups (lanes differing in bits 4,5)
    zacc0 += __shfl_xor(zacc0, 16); zacc0 += __shfl_xor(zacc0, 32);
    zacc1 += __shfl_xor(zacc1, 16); zacc1 += __shfl_xor(zacc1, 32);
    if (lane < 16) { zw[w][0][lane] = zacc0; zw[w][1][lane] = zacc1; }
    __syncthreads();

    if (tid < 64) {
        const int s = tid >> 4, k2 = tid & 15;
        float z = 0.f;
#pragma unroll
        for (int w2 = 0; w2 < 8; ++w2) {
            const int a = sliceOfTile(w2 * 12);
            const int b = sliceOfTile(w2 * 12 + 11);
            if (a == s) z += zw[w2][0][k2];
            if (b == s && b != a) z += zw[w2][1][k2];
        }
        coef[s][k2] = impb[k2] / z;
    }
    __syncthreads();

    // pass 2: dense[n] = sum_t coef[t] * p[t,n]; tokens live across tk lanes
    const float cA = coef[sA][tk];
    const float cB = coef[sB][tk];
    float* pout = part + (size_t)tt * NUSED;
#pragma unroll
    for (int ti = 0; ti < 12; ++ti) {
        const float c = (sliceOfTile(t0 + ti) == sA) ? cA : cB;
        float v0 = p[ti][0] * c, v1 = p[ti][1] * c, v2 = p[ti][2] * c, v3 = p[ti][3] * c;
#pragma unroll
        for (int st = 1; st < 16; st <<= 1) {
            v0 += __shfl_xor(v0, st);
            v1 += __shfl_xor(v1, st);
            v2 += __shfl_xor(v2, st);
            v3 += __shfl_xor(v3, st);
        }
        if (tk == 0)
            *reinterpret_cast<float4*>(&pout[(t0 + ti) * 16 + g * 4]) =
                make_float4(v0, v1, v2, v3);
    }
}

// ---------------- K4a: reduce part 1024 -> 64 rows -------------------------
__launch_bounds__(256)
__global__ void kA(const float* __restrict__ part, float* __restrict__ part2) {
    const int tid = threadIdx.x;
    const int b = blockIdx.x >> 3, g = blockIdx.x & 7;
    const int base = (b * 128 + g * 16) * NUSED;
#pragma unroll
    for (int i = 0; i < 6; ++i) {
        int n = tid + 256 * i;
        float s = 0.f;
#pragma unroll
        for (int r = 0; r < 16; ++r) s += part[base + r * NUSED + n];
        part2[(b * 8 + g) * NUSED + n] = s;
    }
}

// ---------------- K4b: final reduce + top-k sparsify + output --------------
__launch_bounds__(256)
__global__ void kB(const float* __restrict__ part2, float* __restrict__ out) {
    __shared__ float dens[NUSED];
    __shared__ float s_v[4][8];
    __shared__ int   s_n[4][8];
    const int tid = threadIdx.x;
    const int b = blockIdx.x;

#pragma unroll
    for (int i = 0; i < 6; ++i) {
        int n = tid + 256 * i;
        float s = 0.f;
#pragma unroll
        for (int g = 0; g < 8; ++g) s += part2[(b * 8 + g) * NUSED + n];
        dens[n] = s;
    }
    for (int i = tid; i < 1792; i += 256) out[b * 1792 + i] = 0.f;
    __syncthreads();

    const int w = tid >> 6, lane = tid & 63;
    const int soffs[4] = {0, 512, 1024, 1280};
    const int ssz[4]   = {512, 512, 256, 256};
    const int kks[4]   = {8, 8, 4, 6};
    const int ooffs[4] = {0, 512, 1024, 1536};
    const int Sn = ssz[w], soff = soffs[w], kk = kks[w];
    const int nslots = Sn >> 6;

    float v[8];
#pragma unroll
    for (int i = 0; i < 8; ++i)
        v[i] = (i < nslots) ? dens[soff + lane + 64 * i] : -1e30f;

    unsigned rm = 0;
    float ssum = 0.f;
    for (int it = 0; it < kk; ++it) {
        float bv = -1e30f;
        int bn = 0x7fffffff;
#pragma unroll
        for (int i = 0; i < 8; ++i) {
            bool valid = (i < nslots) && !((rm >> i) & 1u);
            if (valid && v[i] > bv) { bv = v[i]; bn = lane + 64 * i; }
        }
#pragma unroll
        for (int off = 32; off; off >>= 1) {
            float ov = __shfl_xor(bv, off);
            int   on = __shfl_xor(bn, off);
            if (ov > bv || (ov == bv && on < bn)) { bv = ov; bn = on; }
        }
        ssum += bv;
        if ((bn & 63) == lane) rm |= 1u << (bn >> 6);
        if (lane == 0) { s_v[w][it] = bv; s_n[w][it] = bn; }
    }
    const float inv = 1.f / (ssum + 1e-8f);
    if (lane < kk) {
        int n = s_n[w][lane];
        float val = s_v[w][lane] * inv;
        out[b * 1792 + ooffs[w] + n] = val;
        if (w == 2) out[b * 1792 + 1280 + n] = val;  // rk = rq
    }
}

extern "C" void kernel_launch(void* const* d_in, const int* in_sizes, int n_in,
                              void* d_out, int out_size, void* d_ws, size_t ws_size,
                              hipStream_t stream) {
    const float* x    = (const float*)d_in[0];
    const float* imp  = (const float*)d_in[1];
    const float* W    = (const float*)d_in[2];
    const float* bias = (const float*)d_in[3];
    const float* emb  = (const float*)d_in[4];
    float* out = (float*)d_out;
    float* ws  = (float*)d_ws;

    short* etfrag = (short*)(ws + WS_ETF);
    float* htp    = ws + WS_HT;
    short* hfrag  = (short*)(ws + WS_HF);
    float* part   = ws + WS_PART;
    float* part2  = ws + WS_PART2;
    short* wfrag  = (short*)(ws + WS_WF);

    k_embpack<<<96, 128, 0, stream>>>(emb, etfrag);
    k_wsplit<<<64, 256, 0, stream>>>(W, wfrag);
    k_gemm1<<<512, 256, 0, stream>>>(x, wfrag, htp);
    k_hfix<<<512, 256, 0, stream>>>(htp, bias, hfrag);
    k_route2<<<1024, 512, 0, stream>>>(hfrag, etfrag, imp, part);
    kA<<<64, 256, 0, stream>>>(part, part2);
    kB<<<8, 256, 0, stream>>>(part2, out);
}

// Round 7
// 77.415 us; speedup vs baseline: 2.9952x; 1.1293x over previous
//
#include <hip/hip_runtime.h>
#include <hip/hip_bf16.h>

#define B_    8
#define S_    2048
#define D_    2048
#define DS_   64
#define NUSED 1536
#define TOK   16384  // B_*S_

typedef __attribute__((ext_vector_type(8))) short bf16x8;
typedef __attribute__((ext_vector_type(4))) float f32x4;

// ws layout (float offsets)
static constexpr int WS_ETF  = 0;          // etfrag: 196608 shorts (98304 f)
static constexpr int WS_HT   = 98304;      // htp[2][64][16384] f32
static constexpr int WS_PART = 2195456;    // part[1024][1536]
static constexpr int WS_PART2= 3768320;    // part2[64][1536]
static constexpr int WS_WF   = 3866624;    // wfrag: 262144 shorts

typedef __attribute__((address_space(1))) const void g_void;
typedef __attribute__((address_space(3))) void l_void;

__device__ inline short bf_hi(float f, float& rhi) {
    __hip_bfloat16 h = __float2bfloat16(f);
    rhi = __bfloat162float(h);
    return __builtin_bit_cast(short, h);
}
__device__ inline short bf_of(float f) {
    __hip_bfloat16 h = __float2bfloat16(f);
    return __builtin_bit_cast(short, h);
}
__device__ inline int sliceOfTile(int tile) {
    return tile < 32 ? 0 : tile < 64 ? 1 : tile < 80 ? 2 : 3;
}

// ---------------- K_pre: fused embpack (blocks 0..47) + wsplit (48..111) ---
// embpack: 2 tiles/block; etfrag[tile 96][kh 2][lane 64][8hi|8lo]
// wsplit:  wfrag[kstep 64][msub 4][hi 512|lo 512 shorts], lane-contiguous 16B
__launch_bounds__(256)
__global__ void k_pre(const float* __restrict__ emb, const float* __restrict__ W,
                      short* __restrict__ etfrag, short* __restrict__ wfrag) {
    __shared__ float red[2][16][8];
    __shared__ float rn[2][16];
    const int tid = threadIdx.x;
    if (blockIdx.x < 48) {
        const int tl = tid >> 7, tid2 = tid & 127;
        const int kh = tid2 >> 6, lane = tid2 & 63;
        const int tile = blockIdx.x * 2 + tl;
        const int nl = lane & 15;
        const int n = tile * 16 + nl;
        const int kb = kh * 32 + (lane >> 4) * 8;
        const float* ep = emb + n * DS_ + kb;
        float4 a = *reinterpret_cast<const float4*>(ep);
        float4 b = *reinterpret_cast<const float4*>(ep + 4);
        float f[8] = {a.x, a.y, a.z, a.w, b.x, b.y, b.z, b.w};
        float ss = 0.f;
#pragma unroll
        for (int j = 0; j < 8; ++j) ss += f[j] * f[j];
        red[tl][nl][kh * 4 + (lane >> 4)] = ss;
        __syncthreads();
        if (tid2 < 16) {
            float s = 0.f;
#pragma unroll
            for (int j = 0; j < 8; ++j) s += red[tl][tid2][j];
            rn[tl][tid2] = 1.0f / sqrtf(s);
        }
        __syncthreads();
        const float r0 = rn[tl][nl];
        bf16x8 hi, lo;
#pragma unroll
        for (int j = 0; j < 8; ++j) {
            float v = f[j] * r0, r;
            hi[j] = bf_hi(v, r);
            lo[j] = bf_of(v - r);
        }
        short* dst = etfrag + (size_t)((tile * 2 + kh) * 64 + lane) * 16;
        *reinterpret_cast<bf16x8*>(dst)     = hi;
        *reinterpret_cast<bf16x8*>(dst + 8) = lo;
    } else {
        const int kstep = blockIdx.x - 48;
        const int msub = tid >> 6, lane = tid & 63;
        const int m = msub * 16 + (lane & 15);
        const float* wp = W + m * D_ + kstep * 32 + (lane >> 4) * 8;
        float4 a = *reinterpret_cast<const float4*>(wp);
        float4 b = *reinterpret_cast<const float4*>(wp + 4);
        float f[8] = {a.x, a.y, a.z, a.w, b.x, b.y, b.z, b.w};
        bf16x8 hi, lo;
#pragma unroll
        for (int j = 0; j < 8; ++j) {
            float r;
            hi[j] = bf_hi(f[j], r);
            lo[j] = bf_of(f[j] - r);
        }
        short* base = wfrag + (size_t)(kstep * 4 + msub) * 1024;
        *reinterpret_cast<bf16x8*>(base + lane * 8)       = hi;
        *reinterpret_cast<bf16x8*>(base + 512 + lane * 8) = lo;
    }
}

// ---------------- K2: h^T = W @ x^T, split-bf16 MFMA, LDS W, 2-ks groups ---
#define MFMA16(A, Bv, C) __builtin_amdgcn_mfma_f32_16x16x32_bf16(A, Bv, C, 0, 0, 0)

__launch_bounds__(256, 2)
__global__ void k_gemm1(const float* __restrict__ x, const short* __restrict__ wfrag,
                        float* __restrict__ htp) {
    __shared__ short wlds[2][2][4096];   // [buf][ks-in-group][4096 shorts] = 32 KB

    const int tid   = threadIdx.x;
    const int split = blockIdx.x & 1;
    const int tb    = (blockIdx.x >> 1) * 64;
    const int wave  = tid >> 6, lane = tid & 63;
    const int tok   = tb + wave * 16 + (lane & 15);

    const float* xp   = x + (size_t)tok * D_ + split * 1024 + (lane >> 4) * 8;
    const short* wsrc = wfrag + (size_t)(split * 32) * 4096;

    f32x4 acc0 = {0.f, 0.f, 0.f, 0.f};
    f32x4 acc1 = acc0, acc2 = acc0, acc3 = acc0;

#define STAGE(g, buf)                                                                        \
    {                                                                                        \
        const short* s0 = wsrc + (size_t)(2 * (g)) * 4096;                                   \
        __builtin_amdgcn_global_load_lds((g_void*)(s0 + tid * 8),                            \
                                         (l_void*)(&wlds[buf][0][tid * 8]), 16, 0, 0);       \
        __builtin_amdgcn_global_load_lds((g_void*)(s0 + 2048 + tid * 8),                     \
                                         (l_void*)(&wlds[buf][0][2048 + tid * 8]), 16, 0, 0);\
        __builtin_amdgcn_global_load_lds((g_void*)(s0 + 4096 + tid * 8),                     \
                                         (l_void*)(&wlds[buf][1][tid * 8]), 16, 0, 0);       \
        __builtin_amdgcn_global_load_lds((g_void*)(s0 + 6144 + tid * 8),                     \
                                         (l_void*)(&wlds[buf][1][2048 + tid * 8]), 16, 0, 0);\
    }

    STAGE(0, 0);
    float4 xc0 = *reinterpret_cast<const float4*>(xp);
    float4 xc1 = *reinterpret_cast<const float4*>(xp + 4);
    float4 xc2 = *reinterpret_cast<const float4*>(xp + 32);
    float4 xc3 = *reinterpret_cast<const float4*>(xp + 36);

#pragma unroll 2
    for (int g = 0; g < 16; ++g) {
        __syncthreads();   // group g's W staged + group g's x drained
        const int buf = g & 1;
        float4 xn0, xn1, xn2, xn3;
        if (g < 15) {      // issue group g+1: W -> LDS(buf^1), x -> regs
            STAGE(g + 1, buf ^ 1);
            const float* nxp = xp + (size_t)(g + 1) * 64;
            xn0 = *reinterpret_cast<const float4*>(nxp);
            xn1 = *reinterpret_cast<const float4*>(nxp + 4);
            xn2 = *reinterpret_cast<const float4*>(nxp + 32);
            xn3 = *reinterpret_cast<const float4*>(nxp + 36);
        }
#pragma unroll
        for (int kk = 0; kk < 2; ++kk) {
            const float4 va = kk ? xc2 : xc0;
            const float4 vb = kk ? xc3 : xc1;
            float xf[8] = {va.x, va.y, va.z, va.w, vb.x, vb.y, vb.z, vb.w};
            bf16x8 bh, bl;
#pragma unroll
            for (int j = 0; j < 8; ++j) {
                float r;
                bh[j] = bf_hi(xf[j], r);
                bl[j] = bf_of(xf[j] - r);
            }
            const short* wl = &wlds[buf][kk][0];
            bf16x8 ah0 = *reinterpret_cast<const bf16x8*>(wl +    0 + lane * 8);
            bf16x8 al0 = *reinterpret_cast<const bf16x8*>(wl +  512 + lane * 8);
            bf16x8 ah1 = *reinterpret_cast<const bf16x8*>(wl + 1024 + lane * 8);
            bf16x8 al1 = *reinterpret_cast<const bf16x8*>(wl + 1536 + lane * 8);
            bf16x8 ah2 = *reinterpret_cast<const bf16x8*>(wl + 2048 + lane * 8);
            bf16x8 al2 = *reinterpret_cast<const bf16x8*>(wl + 2560 + lane * 8);
            bf16x8 ah3 = *reinterpret_cast<const bf16x8*>(wl + 3072 + lane * 8);
            bf16x8 al3 = *reinterpret_cast<const bf16x8*>(wl + 3584 + lane * 8);

            acc0 = MFMA16(ah0, bh, acc0);
            acc1 = MFMA16(ah1, bh, acc1);
            acc2 = MFMA16(ah2, bh, acc2);
            acc3 = MFMA16(ah3, bh, acc3);
            acc0 = MFMA16(al0, bh, acc0);
            acc1 = MFMA16(al1, bh, acc1);
            acc2 = MFMA16(al2, bh, acc2);
            acc3 = MFMA16(al3, bh, acc3);
            acc0 = MFMA16(ah0, bl, acc0);
            acc1 = MFMA16(ah1, bl, acc1);
            acc2 = MFMA16(ah2, bl, acc2);
            acc3 = MFMA16(ah3, bl, acc3);
        }
        if (g < 15) { xc0 = xn0; xc1 = xn1; xc2 = xn2; xc3 = xn3; }
    }

    const int row0 = split * 64 + (lane >> 4) * 4;
    const int col  = tb + wave * 16 + (lane & 15);
#pragma unroll
    for (int r = 0; r < 4; ++r) {
        htp[(size_t)(row0 +  0 + r) * TOK + col] = acc0[r];
        htp[(size_t)(row0 + 16 + r) * TOK + col] = acc1[r];
        htp[(size_t)(row0 + 32 + r) * TOK + col] = acc2[r];
        htp[(size_t)(row0 + 48 + r) * TOK + col] = acc3[r];
    }
}

// ---------------- K3: MFMA routing; h split-sum+bias fused in prologue -----
// Block = 16 tokens (tile tt). 8 waves x 12 neuron-tiles each.
__launch_bounds__(512, 2)
__global__ void k_route2(const float* __restrict__ htp, const float* __restrict__ bias,
                         const short* __restrict__ etfrag, const float* __restrict__ imp,
                         float* __restrict__ part) {
    __shared__ float h_lds[64][16];
    __shared__ float zw[8][2][16];
    __shared__ float coef[4][16];
    __shared__ float impb[16];

    const int tid = threadIdx.x;
    const int w = tid >> 6, lane = tid & 63;
    const int tt = blockIdx.x;
    const int tk = lane & 15, g = lane >> 4;

    // prologue: h = htp[split0] + htp[split1] + bias -> h_lds[64][16]
    if (tid < 256) {
        const int k = tid >> 2, t4 = (tid & 3) << 2;
        const float4* hp4 = reinterpret_cast<const float4*>(htp);
        const int col = tt * 4 + (tid & 3);
        float4 a = hp4[(size_t)k * 4096 + col];
        float4 b = hp4[(size_t)(k + 64) * 4096 + col];
        float bk = bias[k];
        float4 s;
        s.x = a.x + b.x + bk;
        s.y = a.y + b.y + bk;
        s.z = a.z + b.z + bk;
        s.w = a.w + b.w + bk;
        *reinterpret_cast<float4*>(&h_lds[k][t4]) = s;
    }
    if (tid < 16) impb[tid] = imp[tt * 16 + tid];
    __syncthreads();

    // B fragments from h_lds (identical values to the old hfix output)
    bf16x8 bh0, bl0, bh1, bl1;
#pragma unroll
    for (int j = 0; j < 8; ++j) {
        float r;
        float v0 = h_lds[g * 8 + j][tk];
        bh0[j] = bf_hi(v0, r);
        bl0[j] = bf_of(v0 - r);
        float v1 = h_lds[32 + g * 8 + j][tk];
        bh1[j] = bf_hi(v1, r);
        bl1[j] = bf_of(v1 - r);
    }

    const int t0 = w * 12;
    const int sA = sliceOfTile(t0);
    const int sB = sliceOfTile(t0 + 11);
    float zacc0 = 0.f, zacc1 = 0.f;
    float p[12][4];   // fp32 p, statically indexed (full unroll)

    const short* ep = etfrag + (size_t)t0 * 2048 + lane * 16;
#pragma unroll
    for (int ti = 0; ti < 12; ++ti) {
        const short* cp = ep + (size_t)ti * 2048;
        bf16x8 ah0 = *reinterpret_cast<const bf16x8*>(cp);
        bf16x8 al0 = *reinterpret_cast<const bf16x8*>(cp + 8);
        bf16x8 ah1 = *reinterpret_cast<const bf16x8*>(cp + 1024);
        bf16x8 al1 = *reinterpret_cast<const bf16x8*>(cp + 1032);
        f32x4 a0 = {0.f, 0.f, 0.f, 0.f};
        f32x4 a1 = {0.f, 0.f, 0.f, 0.f};
        a0 = MFMA16(ah0, bh0, a0);
        a1 = MFMA16(ah1, bh1, a1);
        a0 = MFMA16(al0, bh0, a0);
        a1 = MFMA16(al1, bh1, a1);
        a0 = MFMA16(ah0, bl0, a0);
        a1 = MFMA16(ah1, bl1, a1);
        const float p0 = __expf(a0[0] + a1[0]);
        const float p1 = __expf(a0[1] + a1[1]);
        const float p2 = __expf(a0[2] + a1[2]);
        const float p3 = __expf(a0[3] + a1[3]);
        p[ti][0] = p0; p[ti][1] = p1; p[ti][2] = p2; p[ti][3] = p3;
        const float zs = (p0 + p1) + (p2 + p3);
        if (sliceOfTile(t0 + ti) == sA) zacc0 += zs; else zacc1 += zs;
    }

    // z: reduce across the 4 row-groups (lanes differing in bits 4,5)
    zacc0 += __shfl_xor(zacc0, 16); zacc0 += __shfl_xor(zacc0, 32);
    zacc1 += __shfl_xor(zacc1, 16); zacc1 += __shfl_xor(zacc1, 32);
    if (lane < 16) { zw[w][0][lane] = zacc0; zw[w][1][lane] = zacc1; }
    __syncthreads();

    if (tid < 64) {
        const int s = tid >> 4, k2 = tid & 15;
        float z = 0.f;
#pragma unroll
        for (int w2 = 0; w2 < 8; ++w2) {
            const int a = sliceOfTile(w2 * 12);
            const int b = sliceOfTile(w2 * 12 + 11);
            if (a == s) z += zw[w2][0][k2];
            if (b == s && b != a) z += zw[w2][1][k2];
        }
        coef[s][k2] = impb[k2] / z;
    }
    __syncthreads();

    // pass 2: dense[n] = sum_t coef[t] * p[t,n]; tokens live across tk lanes
    const float cA = coef[sA][tk];
    const float cB = coef[sB][tk];
    float* pout = part + (size_t)tt * NUSED;
#pragma unroll
    for (int ti = 0; ti < 12; ++ti) {
        const float c = (sliceOfTile(t0 + ti) == sA) ? cA : cB;
        float v0 = p[ti][0] * c, v1 = p[ti][1] * c, v2 = p[ti][2] * c, v3 = p[ti][3] * c;
#pragma unroll
        for (int st = 1; st < 16; st <<= 1) {
            v0 += __shfl_xor(v0, st);
            v1 += __shfl_xor(v1, st);
            v2 += __shfl_xor(v2, st);
            v3 += __shfl_xor(v3, st);
        }
        if (tk == 0)
            *reinterpret_cast<float4*>(&pout[(t0 + ti) * 16 + g * 4]) =
                make_float4(v0, v1, v2, v3);
    }
}

// ---------------- K4a: reduce part 1024 -> 64 rows -------------------------
__launch_bounds__(256)
__global__ void kA(const float* __restrict__ part, float* __restrict__ part2) {
    const int tid = threadIdx.x;
    const int b = blockIdx.x >> 3, g = blockIdx.x & 7;
    const int base = (b * 128 + g * 16) * NUSED;
#pragma unroll
    for (int i = 0; i < 6; ++i) {
        int n = tid + 256 * i;
        float s = 0.f;
#pragma unroll
        for (int r = 0; r < 16; ++r) s += part[base + r * NUSED + n];
        part2[(b * 8 + g) * NUSED + n] = s;
    }
}

// ---------------- K4b: final reduce + top-k sparsify + output --------------
__launch_bounds__(256)
__global__ void kB(const float* __restrict__ part2, float* __restrict__ out) {
    __shared__ float dens[NUSED];
    __shared__ float s_v[4][8];
    __shared__ int   s_n[4][8];
    const int tid = threadIdx.x;
    const int b = blockIdx.x;

#pragma unroll
    for (int i = 0; i < 6; ++i) {
        int n = tid + 256 * i;
        float s = 0.f;
#pragma unroll
        for (int g = 0; g < 8; ++g) s += part2[(b * 8 + g) * NUSED + n];
        dens[n] = s;
    }
    for (int i = tid; i < 1792; i += 256) out[b * 1792 + i] = 0.f;
    __syncthreads();

    const int w = tid >> 6, lane = tid & 63;
    const int soffs[4] = {0, 512, 1024, 1280};
    const int ssz[4]   = {512, 512, 256, 256};
    const int kks[4]   = {8, 8, 4, 6};
    const int ooffs[4] = {0, 512, 1024, 1536};
    const int Sn = ssz[w], soff = soffs[w], kk = kks[w];
    const int nslots = Sn >> 6;

    float v[8];
#pragma unroll
    for (int i = 0; i < 8; ++i)
        v[i] = (i < nslots) ? dens[soff + lane + 64 * i] : -1e30f;

    unsigned rm = 0;
    float ssum = 0.f;
    for (int it = 0; it < kk; ++it) {
        float bv = -1e30f;
        int bn = 0x7fffffff;
#pragma unroll
        for (int i = 0; i < 8; ++i) {
            bool valid = (i < nslots) && !((rm >> i) & 1u);
            if (valid && v[i] > bv) { bv = v[i]; bn = lane + 64 * i; }
        }
#pragma unroll
        for (int off = 32; off; off >>= 1) {
            float ov = __shfl_xor(bv, off);
            int   on = __shfl_xor(bn, off);
            if (ov > bv || (ov == bv && on < bn)) { bv = ov; bn = on; }
        }
        ssum += bv;
        if ((bn & 63) == lane) rm |= 1u << (bn >> 6);
        if (lane == 0) { s_v[w][it] = bv; s_n[w][it] = bn; }
    }
    const float inv = 1.f / (ssum + 1e-8f);
    if (lane < kk) {
        int n = s_n[w][lane];
        float val = s_v[w][lane] * inv;
        out[b * 1792 + ooffs[w] + n] = val;
        if (w == 2) out[b * 1792 + 1280 + n] = val;  // rk = rq
    }
}

extern "C" void kernel_launch(void* const* d_in, const int* in_sizes, int n_in,
                              void* d_out, int out_size, void* d_ws, size_t ws_size,
                              hipStream_t stream) {
    const float* x    = (const float*)d_in[0];
    const float* imp  = (const float*)d_in[1];
    const float* W    = (const float*)d_in[2];
    const float* bias = (const float*)d_in[3];
    const float* emb  = (const float*)d_in[4];
    float* out = (float*)d_out;
    float* ws  = (float*)d_ws;

    short* etfrag = (short*)(ws + WS_ETF);
    float* htp    = ws + WS_HT;
    float* part   = ws + WS_PART;
    float* part2  = ws + WS_PART2;
    short* wfrag  = (short*)(ws + WS_WF);

    k_pre<<<112, 256, 0, stream>>>(emb, W, etfrag, wfrag);
    k_gemm1<<<512, 256, 0, stream>>>(x, wfrag, htp);
    k_route2<<<1024, 512, 0, stream>>>(htp, bias, etfrag, imp, part);
    kA<<<64, 256, 0, stream>>>(part, part2);
    kB<<<8, 256, 0, stream>>>(part2, out);
}